// Round 1
// baseline (4544.614 us; speedup 1.0000x reference)
//
#include <hip/hip_runtime.h>
#include <hip/hip_bf16.h>
#include <math.h>

#define N_NODES   100000
#define N_EDGES   600000
#define NG        64
#define H         128
#define STEPS     4
#define FB        90
#define FV        20
#define NN        (2*N_NODES)   /* 200000 combined nodes */
#define EE        (2*N_EDGES)   /* 1200000 combined edges */

static __device__ __forceinline__ float bf16_lo(unsigned u){ return __uint_as_float(u << 16); }
static __device__ __forceinline__ float bf16_hi(unsigned u){ return __uint_as_float(u & 0xffff0000u); }

// ---------------- CSR construction ----------------

__global__ void deg_kernel(const int* __restrict__ eib, const int* __restrict__ eiv,
                           int* __restrict__ deg){
    int e = blockIdx.x*blockDim.x + threadIdx.x;
    if (e >= EE) return;
    int d;
    if (e < N_EDGES) d = eib[N_EDGES + e];
    else             d = eiv[N_EDGES + (e - N_EDGES)] + N_NODES;
    atomicAdd(&deg[d], 1);
}

// single-block exclusive scan over NN degrees -> row_ptr (and cursor copy)
__global__ void scan_kernel(const int* __restrict__ deg, int* __restrict__ row_ptr,
                            int* __restrict__ cursor){
    __shared__ int sums[1024];
    const int CH = (NN + 1023)/1024;   // 196
    int t = threadIdx.x;
    int base = t*CH;
    int s = 0;
    for (int i = 0; i < CH; ++i){ int idx = base + i; if (idx < NN) s += deg[idx]; }
    sums[t] = s; __syncthreads();
    for (int off = 1; off < 1024; off <<= 1){
        int v = 0; if (t >= off) v = sums[t-off];
        __syncthreads();
        if (t >= off) sums[t] += v;
        __syncthreads();
    }
    int prefix = (t == 0) ? 0 : sums[t-1];
    for (int i = 0; i < CH; ++i){
        int idx = base + i;
        if (idx < NN){
            int d = deg[idx];
            row_ptr[idx] = prefix; cursor[idx] = prefix;
            prefix += d;
        }
    }
    if (t == 1023) row_ptr[NN] = sums[1023];
}

__global__ void csr_fill_kernel(const int* __restrict__ eib, const int* __restrict__ eiv,
                                int* __restrict__ cursor, int* __restrict__ csr_src){
    int e = blockIdx.x*blockDim.x + threadIdx.x;
    if (e >= EE) return;
    int s, d;
    if (e < N_EDGES){ s = eib[e];                 d = eib[N_EDGES + e]; }
    else { int e2 = e - N_EDGES; s = eiv[e2] + N_NODES; d = eiv[N_EDGES + e2] + N_NODES; }
    int pos = atomicAdd(&cursor[d], 1);
    csr_src[pos] = s;
}

// ---------------- weight prep ----------------

// w_ih/w_hh are [3H, H]; produce [H, 3H] transposed copies for coalesced GEMM access
__global__ void transpose_kernel(const float* __restrict__ w_ih, const float* __restrict__ w_hh,
                                 float* __restrict__ wihT, float* __restrict__ whhT){
    int idx = blockIdx.x*blockDim.x + threadIdx.x;
    if (idx >= 3*H*H) return;
    int o = idx / H, k = idx - o*H;
    wihT[k*(3*H) + o] = w_ih[idx];
    whhT[k*(3*H) + o] = w_hh[idx];
}

// ---------------- embedding: h = relu(x @ W_emb) ----------------

__global__ __launch_bounds__(128) void emb_kernel(const float* __restrict__ xb, const float* __restrict__ xv,
                                                  const float* __restrict__ Wb, const float* __restrict__ Wv,
                                                  float* __restrict__ h){
    __shared__ float xs[8][FB];
    int j = threadIdx.x;
    int n0 = blockIdx.x * 8;
    const float* x; const float* W; int K; int xoff;
    if (n0 < N_NODES){ x = xb; W = Wb; K = FB; xoff = n0; }
    else             { x = xv; W = Wv; K = FV; xoff = n0 - N_NODES; }
    for (int i = j; i < 8*K; i += 128){ int r = i / K, c = i - r*K; xs[r][c] = x[(xoff + r)*K + c]; }
    __syncthreads();
    float acc[8];
    #pragma unroll
    for (int n = 0; n < 8; ++n) acc[n] = 0.f;
    for (int k = 0; k < K; ++k){
        float w = W[k*H + j];
        #pragma unroll
        for (int n = 0; n < 8; ++n) acc[n] = fmaf(xs[n][k], w, acc[n]);
    }
    #pragma unroll
    for (int n = 0; n < 8; ++n) h[(size_t)(n0 + n)*H + j] = fmaxf(acc[n], 0.f);
}

// ---------------- m = h @ ggc_weight[step]  (bf16 out) ----------------

__global__ __launch_bounds__(128) void mgemm_kernel(const float* __restrict__ h, const float* __restrict__ Wg,
                                                    __hip_bfloat16* __restrict__ m){
    __shared__ float hs[16][H];
    int j = threadIdx.x;
    int n0 = blockIdx.x * 16;
    for (int r = 0; r < 16; ++r) hs[r][j] = h[(size_t)(n0 + r)*H + j];
    __syncthreads();
    float acc[16];
    #pragma unroll
    for (int n = 0; n < 16; ++n) acc[n] = 0.f;
    for (int k = 0; k < H; k += 4){
        float w0 = Wg[(k+0)*H + j];
        float w1 = Wg[(k+1)*H + j];
        float w2 = Wg[(k+2)*H + j];
        float w3 = Wg[(k+3)*H + j];
        #pragma unroll
        for (int n = 0; n < 16; ++n){
            float4 hv = *reinterpret_cast<const float4*>(&hs[n][k]);
            acc[n] = fmaf(hv.x, w0, fmaf(hv.y, w1, fmaf(hv.z, w2, fmaf(hv.w, w3, acc[n]))));
        }
    }
    #pragma unroll
    for (int n = 0; n < 16; ++n) m[(size_t)(n0 + n)*H + j] = __float2bfloat16(acc[n]);
}

// ---------------- agg[dst] = sum_{e in CSR[dst]} m[src(e)]  ----------------

__global__ __launch_bounds__(256) void agg_kernel(const __hip_bfloat16* __restrict__ m,
                                                  const int* __restrict__ row_ptr,
                                                  const int* __restrict__ csr_src,
                                                  float* __restrict__ agg){
    int wid  = threadIdx.x >> 6;
    int lane = threadIdx.x & 63;
    int node = blockIdx.x*4 + wid;
    int beg = row_ptr[node], end = row_ptr[node+1];
    float a0 = 0.f, a1 = 0.f;
    const unsigned* mbase = reinterpret_cast<const unsigned*>(m);
    for (int e = beg; e < end; ++e){
        int s = csr_src[e];
        unsigned u = mbase[(size_t)s*(H/2) + lane];
        a0 += bf16_lo(u); a1 += bf16_hi(u);
    }
    float2* outp = reinterpret_cast<float2*>(agg + (size_t)node*H);
    outp[lane] = make_float2(a0, a1);
}

// ---------------- fused GRU: gi = agg@wihT, gh = h@whhT, gates, in-place h ----------------

__global__ __launch_bounds__(256) void gru_kernel(const float* __restrict__ agg, float* __restrict__ h,
                                                  const float* __restrict__ wihT, const float* __restrict__ whhT,
                                                  const float* __restrict__ b_ih, const float* __restrict__ b_hh){
    __shared__ float as[16][H];
    __shared__ float hs[16][H];
    int c  = threadIdx.x & 127;
    int rg = threadIdx.x >> 7;           // 0..1, 8 nodes each
    int n0 = blockIdx.x * 16;
    for (int r = rg*8; r < rg*8 + 8; ++r){
        as[r][c] = agg[(size_t)(n0 + r)*H + c];
        hs[r][c] = h[(size_t)(n0 + r)*H + c];
    }
    __syncthreads();
    float ai0[8], ai1[8], ai2[8], ah0[8], ah1[8], ah2[8];
    #pragma unroll
    for (int n = 0; n < 8; ++n){ ai0[n]=ai1[n]=ai2[n]=0.f; ah0[n]=ah1[n]=ah2[n]=0.f; }
    for (int k = 0; k < H; k += 4){
        float wi0[4], wi1[4], wi2[4], wh0[4], wh1[4], wh2[4];
        #pragma unroll
        for (int q = 0; q < 4; ++q){
            const float* wi = wihT + (size_t)(k+q)*384;
            const float* wh = whhT + (size_t)(k+q)*384;
            wi0[q] = wi[c]; wi1[q] = wi[128 + c]; wi2[q] = wi[256 + c];
            wh0[q] = wh[c]; wh1[q] = wh[128 + c]; wh2[q] = wh[256 + c];
        }
        #pragma unroll
        for (int n = 0; n < 8; ++n){
            float4 a4 = *reinterpret_cast<const float4*>(&as[rg*8 + n][k]);
            float4 h4 = *reinterpret_cast<const float4*>(&hs[rg*8 + n][k]);
            ai0[n] = fmaf(a4.x, wi0[0], fmaf(a4.y, wi0[1], fmaf(a4.z, wi0[2], fmaf(a4.w, wi0[3], ai0[n]))));
            ai1[n] = fmaf(a4.x, wi1[0], fmaf(a4.y, wi1[1], fmaf(a4.z, wi1[2], fmaf(a4.w, wi1[3], ai1[n]))));
            ai2[n] = fmaf(a4.x, wi2[0], fmaf(a4.y, wi2[1], fmaf(a4.z, wi2[2], fmaf(a4.w, wi2[3], ai2[n]))));
            ah0[n] = fmaf(h4.x, wh0[0], fmaf(h4.y, wh0[1], fmaf(h4.z, wh0[2], fmaf(h4.w, wh0[3], ah0[n]))));
            ah1[n] = fmaf(h4.x, wh1[0], fmaf(h4.y, wh1[1], fmaf(h4.z, wh1[2], fmaf(h4.w, wh1[3], ah1[n]))));
            ah2[n] = fmaf(h4.x, wh2[0], fmaf(h4.y, wh2[1], fmaf(h4.z, wh2[2], fmaf(h4.w, wh2[3], ah2[n]))));
        }
    }
    float bi0 = b_ih[c], bi1 = b_ih[128 + c], bi2 = b_ih[256 + c];
    float bh0 = b_hh[c], bh1 = b_hh[128 + c], bh2 = b_hh[256 + c];
    #pragma unroll
    for (int n = 0; n < 8; ++n){
        int node = n0 + rg*8 + n;
        float r  = 1.f/(1.f + __expf(-(ai0[n] + bi0 + ah0[n] + bh0)));
        float z  = 1.f/(1.f + __expf(-(ai1[n] + bi1 + ah1[n] + bh1)));
        float nn = tanhf(ai2[n] + bi2 + r*(ah2[n] + bh2));
        float hold = hs[rg*8 + n][c];
        h[(size_t)node*H + c] = (1.f - z)*nn + z*hold;
    }
}

// ---------------- pooling (sorted batch -> run-length partials, few atomics) ----------------

__global__ __launch_bounds__(128) void pool_kernel(const float* __restrict__ h,
                                                   const int* __restrict__ batch_b, const int* __restrict__ batch_v,
                                                   float* __restrict__ pool){
    int j  = threadIdx.x;
    int n0 = blockIdx.x * 32;
    bool voro = (n0 >= N_NODES);
    int colbase = voro ? 128 : 0;
    int gcur = -1; float acc = 0.f;
    for (int r = 0; r < 32; ++r){
        int node = n0 + r;
        int g = voro ? batch_v[node - N_NODES] : batch_b[node];
        if (g != gcur){
            if (gcur >= 0) atomicAdd(&pool[gcur*256 + colbase + j], acc);
            acc = 0.f; gcur = g;
        }
        acc += fmaxf(h[(size_t)node*H + j], 0.f);
    }
    if (gcur >= 0) atomicAdd(&pool[gcur*256 + colbase + j], acc);
}

__global__ __launch_bounds__(256) void cnt_kernel(const int* __restrict__ batch_b, const int* __restrict__ batch_v,
                                                  int* __restrict__ cnt){
    __shared__ int bins[128];
    int t = threadIdx.x;
    if (t < 128) bins[t] = 0;
    __syncthreads();
    int i = blockIdx.x*256 + t;
    if (i < NN){
        int g = (i < N_NODES) ? batch_b[i] : 64 + batch_v[i - N_NODES];
        atomicAdd(&bins[g], 1);
    }
    __syncthreads();
    if (t < 128 && bins[t] > 0) atomicAdd(&cnt[t], bins[t]);
}

// ---------------- output head ----------------

__global__ __launch_bounds__(256) void head_kernel(const float* __restrict__ pool, const int* __restrict__ cnt,
                                                   const float* __restrict__ W1, const float* __restrict__ b1,
                                                   const float* __restrict__ W2, const float* __restrict__ b2,
                                                   float* __restrict__ out){
    __shared__ float gs[256];
    __shared__ float wsum[4];
    int b = blockIdx.x, j = threadIdx.x;
    int c = (j < 128) ? cnt[b] : cnt[64 + b];
    float denom = (float)((c > 1) ? c : 1);
    gs[j] = pool[b*256 + j] / denom;
    __syncthreads();
    float acc = b1[j];
    for (int k = 0; k < 256; ++k) acc = fmaf(gs[k], W1[k*256 + j], acc);
    float y = fmaxf(acc, 0.f) * W2[j];
    #pragma unroll
    for (int off = 32; off > 0; off >>= 1) y += __shfl_down(y, off, 64);
    if ((j & 63) == 0) wsum[j >> 6] = y;
    __syncthreads();
    if (j == 0){
        float x = wsum[0] + wsum[1] + wsum[2] + wsum[3] + b2[0];
        float sp = (x > 0.f) ? x + log1pf(expf(-x)) : log1pf(expf(x));
        out[b] = sp;
    }
}

// ---------------- launch ----------------

extern "C" void kernel_launch(void* const* d_in, const int* in_sizes, int n_in,
                              void* d_out, int out_size, void* d_ws, size_t ws_size,
                              hipStream_t stream){
    const float* x_b      = (const float*)d_in[0];
    const int*   eib      = (const int*)  d_in[1];
    const int*   batch_b  = (const int*)  d_in[2];
    const float* x_v      = (const float*)d_in[3];
    const int*   eiv      = (const int*)  d_in[4];
    const int*   batch_v  = (const int*)  d_in[5];
    const float* W_emb_b  = (const float*)d_in[6];
    const float* W_emb_v  = (const float*)d_in[7];
    const float* ggc_w    = (const float*)d_in[8];
    const float* gru_w_ih = (const float*)d_in[9];
    const float* gru_w_hh = (const float*)d_in[10];
    const float* gru_b_ih = (const float*)d_in[11];
    const float* gru_b_hh = (const float*)d_in[12];
    const float* W1       = (const float*)d_in[13];
    const float* b1       = (const float*)d_in[14];
    const float* W2       = (const float*)d_in[15];
    const float* b2       = (const float*)d_in[16];
    float* out = (float*)d_out;

    char* ws = (char*)d_ws;
    size_t off = 0;
    auto alloc = [&](size_t bytes)->char*{
        char* p = ws + off; off += (bytes + 255)/256*256; return p;
    };
    float*          h       = (float*)          alloc((size_t)NN*H*4);   // 102.4 MB
    float*          agg     = (float*)          alloc((size_t)NN*H*4);   // 102.4 MB
    __hip_bfloat16* m       = (__hip_bfloat16*) alloc((size_t)NN*H*2);   //  51.2 MB
    float*          wihT    = (float*)          alloc((size_t)3*H*H*4);
    float*          whhT    = (float*)          alloc((size_t)3*H*H*4);
    int*            row_ptr = (int*)            alloc((size_t)(NN+1)*4);
    int*            deg     = (int*)            alloc((size_t)NN*4);
    int*            cursor  = (int*)            alloc((size_t)NN*4);
    int*            csr_src = (int*)            alloc((size_t)EE*4);
    float*          pool    = (float*)          alloc((size_t)NG*2*H*4);
    int*            cnt     = (int*)            alloc((size_t)2*NG*4);
    (void)ws_size; (void)in_sizes; (void)n_in; (void)out_size;

    hipMemsetAsync(deg,  0, (size_t)NN*4, stream);
    hipMemsetAsync(pool, 0, (size_t)NG*2*H*4, stream);
    hipMemsetAsync(cnt,  0, (size_t)2*NG*4, stream);

    deg_kernel     <<<(EE + 255)/256, 256, 0, stream>>>(eib, eiv, deg);
    scan_kernel    <<<1, 1024, 0, stream>>>(deg, row_ptr, cursor);
    csr_fill_kernel<<<(EE + 255)/256, 256, 0, stream>>>(eib, eiv, cursor, csr_src);
    transpose_kernel<<<(3*H*H + 255)/256, 256, 0, stream>>>(gru_w_ih, gru_w_hh, wihT, whhT);

    emb_kernel<<<NN/8, 128, 0, stream>>>(x_b, x_v, W_emb_b, W_emb_v, h);

    for (int s = 0; s < STEPS; ++s){
        mgemm_kernel<<<NN/16, 128, 0, stream>>>(h, ggc_w + (size_t)s*H*H, m);
        agg_kernel  <<<NN/4, 256, 0, stream>>>(m, row_ptr, csr_src, agg);
        gru_kernel  <<<NN/16, 256, 0, stream>>>(agg, h, wihT, whhT, gru_b_ih, gru_b_hh);
    }

    pool_kernel<<<NN/32, 128, 0, stream>>>(h, batch_b, batch_v, pool);
    cnt_kernel <<<(NN + 255)/256, 256, 0, stream>>>(batch_b, batch_v, cnt);
    head_kernel<<<NG, 256, 0, stream>>>(pool, cnt, W1, b1, W2, b2, out);
}

// Round 2
// 2376.471 us; speedup vs baseline: 1.9123x; 1.9123x over previous
//
#include <hip/hip_runtime.h>
#include <hip/hip_bf16.h>
#include <math.h>

#define N_NODES   100000
#define N_EDGES   600000
#define NG        64
#define H         128
#define STEPS     4
#define FB        90
#define FV        20
#define NN        (2*N_NODES)   /* 200000 combined nodes */
#define EE        (2*N_EDGES)   /* 1200000 combined edges */
#define BSTR      40            /* LDS row stride in shorts (pad 32->40 kills bank conflicts) */

typedef unsigned short u16;
typedef __attribute__((ext_vector_type(8))) __bf16 bf16x8;
typedef __attribute__((ext_vector_type(4))) float  floatx4;

static __device__ __forceinline__ float bf16_lo(unsigned u){ return __uint_as_float(u << 16); }
static __device__ __forceinline__ float bf16_hi(unsigned u){ return __uint_as_float(u & 0xffff0000u); }
static __device__ __forceinline__ u16 f2bf(float f){
    union { float f; unsigned u; } v; v.f = f;
    unsigned r = v.u + 0x7fffu + ((v.u >> 16) & 1u);
    return (u16)(r >> 16);
}

// ---------------- CSR construction ----------------

__global__ void deg_kernel(const int* __restrict__ eib, const int* __restrict__ eiv,
                           int* __restrict__ deg){
    int e = blockIdx.x*blockDim.x + threadIdx.x;
    if (e >= EE) return;
    int d;
    if (e < N_EDGES) d = eib[N_EDGES + e];
    else             d = eiv[N_EDGES + (e - N_EDGES)] + N_NODES;
    atomicAdd(&deg[d], 1);
}

__global__ void scan_kernel(const int* __restrict__ deg, int* __restrict__ row_ptr,
                            int* __restrict__ cursor){
    __shared__ int sums[1024];
    const int CH = (NN + 1023)/1024;
    int t = threadIdx.x;
    int base = t*CH;
    int s = 0;
    for (int i = 0; i < CH; ++i){ int idx = base + i; if (idx < NN) s += deg[idx]; }
    sums[t] = s; __syncthreads();
    for (int off = 1; off < 1024; off <<= 1){
        int v = 0; if (t >= off) v = sums[t-off];
        __syncthreads();
        if (t >= off) sums[t] += v;
        __syncthreads();
    }
    int prefix = (t == 0) ? 0 : sums[t-1];
    for (int i = 0; i < CH; ++i){
        int idx = base + i;
        if (idx < NN){
            int d = deg[idx];
            row_ptr[idx] = prefix; cursor[idx] = prefix;
            prefix += d;
        }
    }
    if (t == 1023) row_ptr[NN] = sums[1023];
}

__global__ void csr_fill_kernel(const int* __restrict__ eib, const int* __restrict__ eiv,
                                int* __restrict__ cursor, int* __restrict__ csr_src){
    int e = blockIdx.x*blockDim.x + threadIdx.x;
    if (e >= EE) return;
    int s, d;
    if (e < N_EDGES){ s = eib[e];                 d = eib[N_EDGES + e]; }
    else { int e2 = e - N_EDGES; s = eiv[e2] + N_NODES; d = eiv[N_EDGES + e2] + N_NODES; }
    int pos = atomicAdd(&cursor[d], 1);
    csr_src[pos] = s;
}

// ---------------- weight prep (bf16, MFMA-friendly packed layouts) ----------------
// Wg_pack[s][kc][n][kk] = bf16(ggc_w[s][kc*32+kk][n])                  (4*4*128*32)
// Wcat_pack[kc][n][kk]  = bf16(B[kc*32+kk][n]) for the fused GRU GEMM  (8*512*32)
//   B cols: [0,128)=r-sum  [128,256)=z-sum  [256,384)=i_n  [384,512)=h_n
//   B rows: k<128 -> agg coeffs (w_ih), k>=128 -> h coeffs (w_hh)
__global__ void prep_weights_kernel(const float* __restrict__ ggc_w,
                                    const float* __restrict__ w_ih, const float* __restrict__ w_hh,
                                    u16* __restrict__ Wg_pack, u16* __restrict__ Wcat_pack){
    int idx = blockIdx.x*blockDim.x + threadIdx.x;
    if (idx < STEPS*H*H){
        int s = idx / (H*H); int rem = idx % (H*H);
        int k = rem / H, n = rem % H;
        Wg_pack[ (((s*4 + (k>>5))*H) + n)*32 + (k&31) ] = f2bf(ggc_w[idx]);
    }
    if (idx < 512*256){
        int n = idx / 256, k = idx % 256;
        int g = n >> 7, c = n & 127;
        float v;
        if (g == 0)      v = (k < 128) ? w_ih[c*H + k]         : w_hh[c*H + (k-128)];
        else if (g == 1) v = (k < 128) ? w_ih[(128+c)*H + k]   : w_hh[(128+c)*H + (k-128)];
        else if (g == 2) v = (k < 128) ? w_ih[(256+c)*H + k]   : 0.f;
        else             v = (k < 128) ? 0.f                   : w_hh[(256+c)*H + (k-128)];
        Wcat_pack[ (((k>>5)*512) + n)*32 + (k&31) ] = f2bf(v);
    }
}

// ---------------- embedding: h = relu(x @ W_emb), fp32 + bf16 ----------------

__global__ __launch_bounds__(128) void emb_kernel(const float* __restrict__ xb, const float* __restrict__ xv,
                                                  const float* __restrict__ Wb, const float* __restrict__ Wv,
                                                  float* __restrict__ h, u16* __restrict__ hb){
    __shared__ float xs[8][FB];
    int j = threadIdx.x;
    int n0 = blockIdx.x * 8;
    const float* x; const float* W; int K; int xoff;
    if (n0 < N_NODES){ x = xb; W = Wb; K = FB; xoff = n0; }
    else             { x = xv; W = Wv; K = FV; xoff = n0 - N_NODES; }
    for (int i = j; i < 8*K; i += 128){ int r = i / K, c = i - r*K; xs[r][c] = x[(xoff + r)*K + c]; }
    __syncthreads();
    float acc[8];
    #pragma unroll
    for (int n = 0; n < 8; ++n) acc[n] = 0.f;
    for (int k = 0; k < K; ++k){
        float w = W[k*H + j];
        #pragma unroll
        for (int n = 0; n < 8; ++n) acc[n] = fmaf(xs[n][k], w, acc[n]);
    }
    #pragma unroll
    for (int n = 0; n < 8; ++n){
        float v = fmaxf(acc[n], 0.f);
        h [(size_t)(n0 + n)*H + j] = v;
        hb[(size_t)(n0 + n)*H + j] = f2bf(v);
    }
}

// ---------------- m = hb @ ggc_w[step]  (bf16 MFMA, bf16 out) ----------------
// block: 4 waves x 16 rows = 64 rows; N=128 (8 tiles); K=128 (4 chunks of 32)

__global__ __launch_bounds__(256) void mgemm_mfma_kernel(const u16* __restrict__ hb,
                                                         const u16* __restrict__ Wg,   /* [4][128][32] */
                                                         u16* __restrict__ m){
    __shared__ u16 Bs[128*BSTR];
    __shared__ u16 As[64*BSTR];
    const int t = threadIdx.x;
    const int wid = t >> 6, lane = t & 63;
    const int l15 = lane & 15, l4 = lane >> 4;
    const int n0 = blockIdx.x * 64;

    floatx4 acc[8];
    #pragma unroll
    for (int i = 0; i < 8; ++i) acc[i] = (floatx4){0.f,0.f,0.f,0.f};

    for (int kc = 0; kc < 4; ++kc){
        __syncthreads();
        {   // stage B chunk: 128 rows x 32 shorts = 512 int4
            const u16* src = Wg + (size_t)kc*H*32;
            #pragma unroll
            for (int p = 0; p < 2; ++p){
                int i = t + p*256;
                int n = i >> 2, part = i & 3;
                const int4 v = *reinterpret_cast<const int4*>(src + n*32 + part*8);
                *reinterpret_cast<int4*>(&Bs[n*BSTR + part*8]) = v;
            }
        }
        {   // stage A chunk: 64 rows x 32 shorts = 256 int4
            int row = t >> 2, part = t & 3;
            const int4 v = *reinterpret_cast<const int4*>(hb + (size_t)(n0 + row)*H + kc*32 + part*8);
            *reinterpret_cast<int4*>(&As[row*BSTR + part*8]) = v;
        }
        __syncthreads();
        bf16x8 aF = *reinterpret_cast<const bf16x8*>(&As[(wid*16 + l15)*BSTR + l4*8]);
        #pragma unroll
        for (int tt = 0; tt < 8; ++tt){
            bf16x8 bF = *reinterpret_cast<const bf16x8*>(&Bs[(tt*16 + l15)*BSTR + l4*8]);
            acc[tt] = __builtin_amdgcn_mfma_f32_16x16x32_bf16(aF, bF, acc[tt], 0, 0, 0);
        }
    }
    const int rowb = n0 + wid*16 + l4*4;
    #pragma unroll
    for (int tt = 0; tt < 8; ++tt){
        int col = tt*16 + l15;
        #pragma unroll
        for (int rg = 0; rg < 4; ++rg)
            m[(size_t)(rowb + rg)*H + col] = f2bf(acc[tt][rg]);
    }
}

// ---------------- agg[dst] = sum m[src]  (bf16 in, bf16 out) ----------------

__global__ __launch_bounds__(256) void agg_kernel(const u16* __restrict__ m,
                                                  const int* __restrict__ row_ptr,
                                                  const int* __restrict__ csr_src,
                                                  u16* __restrict__ aggb){
    int wid  = threadIdx.x >> 6;
    int lane = threadIdx.x & 63;
    int node = blockIdx.x*4 + wid;
    int beg = row_ptr[node], end = row_ptr[node+1];
    float a0 = 0.f, a1 = 0.f;
    const unsigned* mbase = reinterpret_cast<const unsigned*>(m);
    for (int e = beg; e < end; ++e){
        int s = csr_src[e];
        unsigned u = mbase[(size_t)s*(H/2) + lane];
        a0 += bf16_lo(u); a1 += bf16_hi(u);
    }
    unsigned lo = f2bf(a0), hi = f2bf(a1);
    reinterpret_cast<unsigned*>(aggb)[(size_t)node*(H/2) + lane] = (hi << 16) | lo;
}

// ---------------- fused GRU via MFMA ----------------
// A = [agg | h] bf16, K=256 (8 chunks of 32). B = Wcat_pack, N=512.
// wave w handles rows n0+16w..+15, all 512 cols = 32 accumulator tiles:
//   tiles 0-7: r-sum (full K)   8-15: z-sum (full K)
//   tiles 16-23: i_n (K<128 only, i.e. kc<4)   24-31: h_n (kc>=4 only)
// Gate combine is lane-local (same (row,col) -> same lane across tile groups).

__global__ __launch_bounds__(256) void gru_mfma_kernel(const u16* __restrict__ aggb,
                                                       u16* __restrict__ hb,          /* in (A) + out */
                                                       float* __restrict__ h,         /* fp32 master, in/out */
                                                       const u16* __restrict__ Wcat,  /* [8][512][32] */
                                                       const float* __restrict__ b_ih,
                                                       const float* __restrict__ b_hh){
    __shared__ u16 Bs[512*BSTR];
    __shared__ u16 As[64*BSTR];
    const int t = threadIdx.x;
    const int wid = t >> 6, lane = t & 63;
    const int l15 = lane & 15, l4 = lane >> 4;
    const int n0 = blockIdx.x * 64;

    floatx4 acc[32];
    #pragma unroll
    for (int i = 0; i < 32; ++i) acc[i] = (floatx4){0.f,0.f,0.f,0.f};

    for (int kc = 0; kc < 8; ++kc){
        __syncthreads();
        {   // stage B chunk: 512 rows x 32 shorts = 2048 int4, 8 per thread
            const u16* src = Wcat + (size_t)kc*512*32;
            #pragma unroll
            for (int p = 0; p < 8; ++p){
                int i = t + p*256;
                int n = i >> 2, part = i & 3;
                const int4 v = *reinterpret_cast<const int4*>(src + n*32 + part*8);
                *reinterpret_cast<int4*>(&Bs[n*BSTR + part*8]) = v;
            }
        }
        {   // stage A chunk: 64 rows x 32 shorts
            int row = t >> 2, part = t & 3;
            const u16* srcA = (kc < 4) ? aggb : hb;
            const int4 v = *reinterpret_cast<const int4*>(srcA + (size_t)(n0 + row)*H + (kc & 3)*32 + part*8);
            *reinterpret_cast<int4*>(&As[row*BSTR + part*8]) = v;
        }
        __syncthreads();
        bf16x8 aF = *reinterpret_cast<const bf16x8*>(&As[(wid*16 + l15)*BSTR + l4*8]);
        #pragma unroll
        for (int tt = 0; tt < 16; ++tt){
            bf16x8 bF = *reinterpret_cast<const bf16x8*>(&Bs[(tt*16 + l15)*BSTR + l4*8]);
            acc[tt] = __builtin_amdgcn_mfma_f32_16x16x32_bf16(aF, bF, acc[tt], 0, 0, 0);
        }
        if (kc < 4){
            #pragma unroll
            for (int tt = 16; tt < 24; ++tt){
                bf16x8 bF = *reinterpret_cast<const bf16x8*>(&Bs[(tt*16 + l15)*BSTR + l4*8]);
                acc[tt] = __builtin_amdgcn_mfma_f32_16x16x32_bf16(aF, bF, acc[tt], 0, 0, 0);
            }
        } else {
            #pragma unroll
            for (int tt = 24; tt < 32; ++tt){
                bf16x8 bF = *reinterpret_cast<const bf16x8*>(&Bs[(tt*16 + l15)*BSTR + l4*8]);
                acc[tt] = __builtin_amdgcn_mfma_f32_16x16x32_bf16(aF, bF, acc[tt], 0, 0, 0);
            }
        }
    }

    const int rowb = n0 + wid*16 + l4*4;
    #pragma unroll
    for (int j = 0; j < 8; ++j){
        int col = j*16 + l15;
        float br  = b_ih[col]       + b_hh[col];
        float bz  = b_ih[128 + col] + b_hh[128 + col];
        float bin = b_ih[256 + col];
        float bhn = b_hh[256 + col];
        #pragma unroll
        for (int rg = 0; rg < 4; ++rg){
            int row = rowb + rg;
            float r   = 1.f/(1.f + __expf(-(acc[j][rg]     + br)));
            float z   = 1.f/(1.f + __expf(-(acc[8+j][rg]   + bz)));
            float nn_ = tanhf(acc[16+j][rg] + bin + r*(acc[24+j][rg] + bhn));
            float hold = h[(size_t)row*H + col];
            float hnew = (1.f - z)*nn_ + z*hold;
            h [(size_t)row*H + col] = hnew;
            hb[(size_t)row*H + col] = f2bf(hnew);
        }
    }
}

// ---------------- pooling ----------------

__global__ __launch_bounds__(128) void pool_kernel(const float* __restrict__ h,
                                                   const int* __restrict__ batch_b, const int* __restrict__ batch_v,
                                                   float* __restrict__ pool){
    int j  = threadIdx.x;
    int n0 = blockIdx.x * 32;
    bool voro = (n0 >= N_NODES);
    int colbase = voro ? 128 : 0;
    int gcur = -1; float acc = 0.f;
    for (int r = 0; r < 32; ++r){
        int node = n0 + r;
        int g = voro ? batch_v[node - N_NODES] : batch_b[node];
        if (g != gcur){
            if (gcur >= 0) atomicAdd(&pool[gcur*256 + colbase + j], acc);
            acc = 0.f; gcur = g;
        }
        acc += fmaxf(h[(size_t)node*H + j], 0.f);
    }
    if (gcur >= 0) atomicAdd(&pool[gcur*256 + colbase + j], acc);
}

__global__ __launch_bounds__(256) void cnt_kernel(const int* __restrict__ batch_b, const int* __restrict__ batch_v,
                                                  int* __restrict__ cnt){
    __shared__ int bins[128];
    int t = threadIdx.x;
    if (t < 128) bins[t] = 0;
    __syncthreads();
    int i = blockIdx.x*256 + t;
    if (i < NN){
        int g = (i < N_NODES) ? batch_b[i] : 64 + batch_v[i - N_NODES];
        atomicAdd(&bins[g], 1);
    }
    __syncthreads();
    if (t < 128 && bins[t] > 0) atomicAdd(&cnt[t], bins[t]);
}

// ---------------- output head ----------------

__global__ __launch_bounds__(256) void head_kernel(const float* __restrict__ pool, const int* __restrict__ cnt,
                                                   const float* __restrict__ W1, const float* __restrict__ b1,
                                                   const float* __restrict__ W2, const float* __restrict__ b2,
                                                   float* __restrict__ out){
    __shared__ float gs[256];
    __shared__ float wsum[4];
    int b = blockIdx.x, j = threadIdx.x;
    int c = (j < 128) ? cnt[b] : cnt[64 + b];
    float denom = (float)((c > 1) ? c : 1);
    gs[j] = pool[b*256 + j] / denom;
    __syncthreads();
    float acc = b1[j];
    for (int k = 0; k < 256; ++k) acc = fmaf(gs[k], W1[k*256 + j], acc);
    float y = fmaxf(acc, 0.f) * W2[j];
    #pragma unroll
    for (int off = 32; off > 0; off >>= 1) y += __shfl_down(y, off, 64);
    if ((j & 63) == 0) wsum[j >> 6] = y;
    __syncthreads();
    if (j == 0){
        float x = wsum[0] + wsum[1] + wsum[2] + wsum[3] + b2[0];
        float sp = (x > 0.f) ? x + log1pf(expf(-x)) : log1pf(expf(x));
        out[b] = sp;
    }
}

// ---------------- launch ----------------

extern "C" void kernel_launch(void* const* d_in, const int* in_sizes, int n_in,
                              void* d_out, int out_size, void* d_ws, size_t ws_size,
                              hipStream_t stream){
    const float* x_b      = (const float*)d_in[0];
    const int*   eib      = (const int*)  d_in[1];
    const int*   batch_b  = (const int*)  d_in[2];
    const float* x_v      = (const float*)d_in[3];
    const int*   eiv      = (const int*)  d_in[4];
    const int*   batch_v  = (const int*)  d_in[5];
    const float* W_emb_b  = (const float*)d_in[6];
    const float* W_emb_v  = (const float*)d_in[7];
    const float* ggc_w    = (const float*)d_in[8];
    const float* gru_w_ih = (const float*)d_in[9];
    const float* gru_w_hh = (const float*)d_in[10];
    const float* gru_b_ih = (const float*)d_in[11];
    const float* gru_b_hh = (const float*)d_in[12];
    const float* W1       = (const float*)d_in[13];
    const float* b1       = (const float*)d_in[14];
    const float* W2       = (const float*)d_in[15];
    const float* b2       = (const float*)d_in[16];
    float* out = (float*)d_out;

    char* ws = (char*)d_ws;
    size_t off = 0;
    auto alloc = [&](size_t bytes)->char*{
        char* p = ws + off; off += (bytes + 255)/256*256; return p;
    };
    float* h        = (float*) alloc((size_t)NN*H*4);        // 102.4 MB
    u16*   hb       = (u16*)   alloc((size_t)NN*H*2);        //  51.2 MB
    u16*   aggb     = (u16*)   alloc((size_t)NN*H*2);        //  51.2 MB
    u16*   m        = (u16*)   alloc((size_t)NN*H*2);        //  51.2 MB
    u16*   Wg_pack  = (u16*)   alloc((size_t)STEPS*4*H*32*2);
    u16*   Wcat     = (u16*)   alloc((size_t)8*512*32*2);
    int*   row_ptr  = (int*)   alloc((size_t)(NN+1)*4);
    int*   deg      = (int*)   alloc((size_t)NN*4);
    int*   cursor   = (int*)   alloc((size_t)NN*4);
    int*   csr_src  = (int*)   alloc((size_t)EE*4);
    float* pool     = (float*) alloc((size_t)NG*2*H*4);
    int*   cnt      = (int*)   alloc((size_t)2*NG*4);
    (void)ws_size; (void)in_sizes; (void)n_in; (void)out_size;

    hipMemsetAsync(deg,  0, (size_t)NN*4, stream);
    hipMemsetAsync(pool, 0, (size_t)NG*2*H*4, stream);
    hipMemsetAsync(cnt,  0, (size_t)2*NG*4, stream);

    deg_kernel        <<<(EE + 255)/256, 256, 0, stream>>>(eib, eiv, deg);
    scan_kernel       <<<1, 1024, 0, stream>>>(deg, row_ptr, cursor);
    csr_fill_kernel   <<<(EE + 255)/256, 256, 0, stream>>>(eib, eiv, cursor, csr_src);
    prep_weights_kernel<<<512, 256, 0, stream>>>(ggc_w, gru_w_ih, gru_w_hh, Wg_pack, Wcat);

    emb_kernel<<<NN/8, 128, 0, stream>>>(x_b, x_v, W_emb_b, W_emb_v, h, hb);

    for (int s = 0; s < STEPS; ++s){
        mgemm_mfma_kernel<<<NN/64, 256, 0, stream>>>(hb, Wg_pack + (size_t)s*4*H*32, m);
        agg_kernel       <<<NN/4, 256, 0, stream>>>(m, row_ptr, csr_src, aggb);
        gru_mfma_kernel  <<<NN/64, 256, 0, stream>>>(aggb, hb, h, Wcat, gru_b_ih, gru_b_hh);
    }

    pool_kernel<<<NN/32, 128, 0, stream>>>(h, batch_b, batch_v, pool);
    cnt_kernel <<<(NN + 255)/256, 256, 0, stream>>>(batch_b, batch_v, cnt);
    head_kernel<<<NG, 256, 0, stream>>>(pool, cnt, W1, b1, W2, b2, out);
}

// Round 3
// 1885.975 us; speedup vs baseline: 2.4097x; 1.2601x over previous
//
#include <hip/hip_runtime.h>
#include <hip/hip_bf16.h>
#include <math.h>

#define N_NODES   100000
#define N_EDGES   600000
#define NG        64
#define H         128
#define STEPS     4
#define FB        90
#define FV        20
#define NN        (2*N_NODES)   /* 200000 combined nodes */
#define EE        (2*N_EDGES)   /* 1200000 combined edges */
#define BSTR      40            /* LDS row stride in shorts (pad 32->40 kills bank conflicts) */
#define NBLK      196           /* scan blocks: 196*1024 = 200704 >= NN */
#define NNP       (NBLK*1024)   /* padded degree array length */

typedef unsigned short u16;
typedef __attribute__((ext_vector_type(8))) __bf16 bf16x8;
typedef __attribute__((ext_vector_type(4))) float  floatx4;

static __device__ __forceinline__ float bf16_lo(unsigned u){ return __uint_as_float(u << 16); }
static __device__ __forceinline__ float bf16_hi(unsigned u){ return __uint_as_float(u & 0xffff0000u); }
static __device__ __forceinline__ u16 f2bf(float f){
    union { float f; unsigned u; } v; v.f = f;
    unsigned r = v.u + 0x7fffu + ((v.u >> 16) & 1u);
    return (u16)(r >> 16);
}

// ---------------- CSR construction ----------------

__global__ void deg_kernel(const int* __restrict__ eib, const int* __restrict__ eiv,
                           int* __restrict__ deg){
    int e = blockIdx.x*blockDim.x + threadIdx.x;
    if (e >= EE) return;
    int d;
    if (e < N_EDGES) d = eib[N_EDGES + e];
    else             d = eiv[N_EDGES + (e - N_EDGES)] + N_NODES;
    atomicAdd(&deg[d], 1);
}

// parallel 3-phase exclusive scan over NNP (padded, zero-filled) degrees
__global__ __launch_bounds__(256) void bsum_kernel(const int* __restrict__ deg, int* __restrict__ bsum){
    int t = threadIdx.x;
    int4 v = reinterpret_cast<const int4*>(deg)[blockIdx.x*256 + t];
    int s = v.x + v.y + v.z + v.w;
    __shared__ int ss[256];
    ss[t] = s; __syncthreads();
    for (int off = 128; off > 0; off >>= 1){ if (t < off) ss[t] += ss[t + off]; __syncthreads(); }
    if (t == 0) bsum[blockIdx.x] = ss[0];
}

__global__ __launch_bounds__(256) void bscan_kernel(const int* __restrict__ bsum, int* __restrict__ boff){
    int t = threadIdx.x;
    int v = (t < NBLK) ? bsum[t] : 0;
    __shared__ int ss[256];
    ss[t] = v; __syncthreads();
    for (int off = 1; off < 256; off <<= 1){
        int u = (t >= off) ? ss[t - off] : 0;
        __syncthreads();
        ss[t] += u;
        __syncthreads();
    }
    boff[t] = ss[t] - v;   // exclusive
}

__global__ __launch_bounds__(256) void scan_final_kernel(const int* __restrict__ deg, const int* __restrict__ boff,
                                                         int* __restrict__ row_ptr, int* __restrict__ cursor){
    int t = threadIdx.x, b = blockIdx.x;
    int4 v = reinterpret_cast<const int4*>(deg)[b*256 + t];
    int s = v.x + v.y + v.z + v.w;
    __shared__ int ss[256];
    ss[t] = s; __syncthreads();
    for (int off = 1; off < 256; off <<= 1){
        int u = (t >= off) ? ss[t - off] : 0;
        __syncthreads();
        ss[t] += u;
        __syncthreads();
    }
    int base = boff[b] + ss[t] - s;   // exclusive prefix of element i0
    int i0 = b*1024 + t*4;
    int e0 = base, e1 = e0 + v.x, e2 = e1 + v.y, e3 = e2 + v.z;
    if (i0 < NN){   // NN % 4 == 0 -> all-or-nothing
        int4 w = make_int4(e0, e1, e2, e3);
        reinterpret_cast<int4*>(row_ptr)[i0 >> 2] = w;
        reinterpret_cast<int4*>(cursor)[i0 >> 2]  = w;
    }
    if (b == 0 && t == 0) row_ptr[NN] = EE;   // total degree == edge count, statically known
}

__global__ void csr_fill_kernel(const int* __restrict__ eib, const int* __restrict__ eiv,
                                int* __restrict__ cursor, int* __restrict__ csr_src){
    int e = blockIdx.x*blockDim.x + threadIdx.x;
    if (e >= EE) return;
    int s, d;
    if (e < N_EDGES){ s = eib[e];                 d = eib[N_EDGES + e]; }
    else { int e2 = e - N_EDGES; s = eiv[e2] + N_NODES; d = eiv[N_EDGES + e2] + N_NODES; }
    int pos = atomicAdd(&cursor[d], 1);
    csr_src[pos] = s;
}

// ---------------- weight prep (bf16, MFMA-friendly packed layouts) ----------------
// Wg_pack[s][kc][n][kk] = bf16(ggc_w[s][kc*32+kk][n])                  (4*4*128*32)
// Wcat_pack[kc][n][kk]  = bf16(B[kc*32+kk][n]) for the fused GRU GEMM  (8*512*32)
//   B cols: [0,128)=r-sum  [128,256)=z-sum  [256,384)=i_n  [384,512)=h_n
//   B rows: k<128 -> agg coeffs (w_ih), k>=128 -> h coeffs (w_hh)
__global__ void prep_weights_kernel(const float* __restrict__ ggc_w,
                                    const float* __restrict__ w_ih, const float* __restrict__ w_hh,
                                    u16* __restrict__ Wg_pack, u16* __restrict__ Wcat_pack){
    int idx = blockIdx.x*blockDim.x + threadIdx.x;
    if (idx < STEPS*H*H){
        int s = idx / (H*H); int rem = idx % (H*H);
        int k = rem / H, n = rem % H;
        Wg_pack[ (((s*4 + (k>>5))*H) + n)*32 + (k&31) ] = f2bf(ggc_w[idx]);
    }
    if (idx < 512*256){
        int n = idx / 256, k = idx % 256;
        int g = n >> 7, c = n & 127;
        float v;
        if (g == 0)      v = (k < 128) ? w_ih[c*H + k]         : w_hh[c*H + (k-128)];
        else if (g == 1) v = (k < 128) ? w_ih[(128+c)*H + k]   : w_hh[(128+c)*H + (k-128)];
        else if (g == 2) v = (k < 128) ? w_ih[(256+c)*H + k]   : 0.f;
        else             v = (k < 128) ? 0.f                   : w_hh[(256+c)*H + (k-128)];
        Wcat_pack[ (((k>>5)*512) + n)*32 + (k&31) ] = f2bf(v);
    }
}

// ---------------- embedding: h = relu(x @ W_emb), fp32 + bf16 ----------------

__global__ __launch_bounds__(128) void emb_kernel(const float* __restrict__ xb, const float* __restrict__ xv,
                                                  const float* __restrict__ Wb, const float* __restrict__ Wv,
                                                  float* __restrict__ h, u16* __restrict__ hb){
    __shared__ float xs[8][FB];
    int j = threadIdx.x;
    int n0 = blockIdx.x * 8;
    const float* x; const float* W; int K; int xoff;
    if (n0 < N_NODES){ x = xb; W = Wb; K = FB; xoff = n0; }
    else             { x = xv; W = Wv; K = FV; xoff = n0 - N_NODES; }
    for (int i = j; i < 8*K; i += 128){ int r = i / K, c = i - r*K; xs[r][c] = x[(xoff + r)*K + c]; }
    __syncthreads();
    float acc[8];
    #pragma unroll
    for (int n = 0; n < 8; ++n) acc[n] = 0.f;
    for (int k = 0; k < K; ++k){
        float w = W[k*H + j];
        #pragma unroll
        for (int n = 0; n < 8; ++n) acc[n] = fmaf(xs[n][k], w, acc[n]);
    }
    #pragma unroll
    for (int n = 0; n < 8; ++n){
        float v = fmaxf(acc[n], 0.f);
        h [(size_t)(n0 + n)*H + j] = v;
        hb[(size_t)(n0 + n)*H + j] = f2bf(v);
    }
}

// ---------------- m = hb @ ggc_w[step]  (bf16 MFMA, bf16 out) ----------------

__global__ __launch_bounds__(256) void mgemm_mfma_kernel(const u16* __restrict__ hb,
                                                         const u16* __restrict__ Wg,   /* [4][128][32] */
                                                         u16* __restrict__ m){
    __shared__ u16 Bs[128*BSTR];
    __shared__ u16 As[64*BSTR];
    const int t = threadIdx.x;
    const int wid = t >> 6, lane = t & 63;
    const int l15 = lane & 15, l4 = lane >> 4;
    const int n0 = blockIdx.x * 64;

    floatx4 acc[8];
    #pragma unroll
    for (int i = 0; i < 8; ++i) acc[i] = (floatx4){0.f,0.f,0.f,0.f};

    for (int kc = 0; kc < 4; ++kc){
        __syncthreads();
        {   // stage B chunk: 128 rows x 32 shorts = 512 int4
            const u16* src = Wg + (size_t)kc*H*32;
            #pragma unroll
            for (int p = 0; p < 2; ++p){
                int i = t + p*256;
                int n = i >> 2, part = i & 3;
                const int4 v = *reinterpret_cast<const int4*>(src + n*32 + part*8);
                *reinterpret_cast<int4*>(&Bs[n*BSTR + part*8]) = v;
            }
        }
        {   // stage A chunk: 64 rows x 32 shorts = 256 int4
            int row = t >> 2, part = t & 3;
            const int4 v = *reinterpret_cast<const int4*>(hb + (size_t)(n0 + row)*H + kc*32 + part*8);
            *reinterpret_cast<int4*>(&As[row*BSTR + part*8]) = v;
        }
        __syncthreads();
        bf16x8 aF = *reinterpret_cast<const bf16x8*>(&As[(wid*16 + l15)*BSTR + l4*8]);
        #pragma unroll
        for (int tt = 0; tt < 8; ++tt){
            bf16x8 bF = *reinterpret_cast<const bf16x8*>(&Bs[(tt*16 + l15)*BSTR + l4*8]);
            acc[tt] = __builtin_amdgcn_mfma_f32_16x16x32_bf16(aF, bF, acc[tt], 0, 0, 0);
        }
    }
    const int rowb = n0 + wid*16 + l4*4;
    #pragma unroll
    for (int tt = 0; tt < 8; ++tt){
        int col = tt*16 + l15;
        #pragma unroll
        for (int rg = 0; rg < 4; ++rg)
            m[(size_t)(rowb + rg)*H + col] = f2bf(acc[tt][rg]);
    }
}

// ---------------- agg[dst] = sum m[src]  (bf16 in, bf16 out) ----------------

__global__ __launch_bounds__(256) void agg_kernel(const u16* __restrict__ m,
                                                  const int* __restrict__ row_ptr,
                                                  const int* __restrict__ csr_src,
                                                  u16* __restrict__ aggb){
    int wid  = threadIdx.x >> 6;
    int lane = threadIdx.x & 63;
    int node = blockIdx.x*4 + wid;
    int beg = row_ptr[node], end = row_ptr[node+1];
    float a0 = 0.f, a1 = 0.f;
    const unsigned* mbase = reinterpret_cast<const unsigned*>(m);
    for (int e = beg; e < end; ++e){
        int s = csr_src[e];
        unsigned u = mbase[(size_t)s*(H/2) + lane];
        a0 += bf16_lo(u); a1 += bf16_hi(u);
    }
    unsigned lo = f2bf(a0), hi = f2bf(a1);
    reinterpret_cast<unsigned*>(aggb)[(size_t)node*(H/2) + lane] = (hi << 16) | lo;
}

// ---------------- fused GRU via MFMA ----------------
// A = [agg | h] bf16, K=256 (8 chunks of 32). B = Wcat_pack, N=512.
// wave w handles rows n0+16w..+15, all 512 cols = 32 accumulator tiles:
//   tiles 0-7: r-sum (full K)   8-15: z-sum (full K)
//   tiles 16-23: i_n (kc<4 only)   24-31: h_n (kc>=4 only)

__global__ __launch_bounds__(256) void gru_mfma_kernel(const u16* __restrict__ aggb,
                                                       u16* __restrict__ hb,          /* in (A) + out */
                                                       float* __restrict__ h,         /* fp32 master, in/out */
                                                       const u16* __restrict__ Wcat,  /* [8][512][32] */
                                                       const float* __restrict__ b_ih,
                                                       const float* __restrict__ b_hh){
    __shared__ u16 Bs[512*BSTR];
    __shared__ u16 As[64*BSTR];
    const int t = threadIdx.x;
    const int wid = t >> 6, lane = t & 63;
    const int l15 = lane & 15, l4 = lane >> 4;
    const int n0 = blockIdx.x * 64;

    floatx4 acc[32];
    #pragma unroll
    for (int i = 0; i < 32; ++i) acc[i] = (floatx4){0.f,0.f,0.f,0.f};

    for (int kc = 0; kc < 8; ++kc){
        __syncthreads();
        {   // stage B chunk: 512 rows x 32 shorts = 2048 int4, 8 per thread
            const u16* src = Wcat + (size_t)kc*512*32;
            #pragma unroll
            for (int p = 0; p < 8; ++p){
                int i = t + p*256;
                int n = i >> 2, part = i & 3;
                const int4 v = *reinterpret_cast<const int4*>(src + n*32 + part*8);
                *reinterpret_cast<int4*>(&Bs[n*BSTR + part*8]) = v;
            }
        }
        {   // stage A chunk: 64 rows x 32 shorts
            int row = t >> 2, part = t & 3;
            const u16* srcA = (kc < 4) ? aggb : hb;
            const int4 v = *reinterpret_cast<const int4*>(srcA + (size_t)(n0 + row)*H + (kc & 3)*32 + part*8);
            *reinterpret_cast<int4*>(&As[row*BSTR + part*8]) = v;
        }
        __syncthreads();
        bf16x8 aF = *reinterpret_cast<const bf16x8*>(&As[(wid*16 + l15)*BSTR + l4*8]);
        #pragma unroll
        for (int tt = 0; tt < 16; ++tt){
            bf16x8 bF = *reinterpret_cast<const bf16x8*>(&Bs[(tt*16 + l15)*BSTR + l4*8]);
            acc[tt] = __builtin_amdgcn_mfma_f32_16x16x32_bf16(aF, bF, acc[tt], 0, 0, 0);
        }
        if (kc < 4){
            #pragma unroll
            for (int tt = 16; tt < 24; ++tt){
                bf16x8 bF = *reinterpret_cast<const bf16x8*>(&Bs[(tt*16 + l15)*BSTR + l4*8]);
                acc[tt] = __builtin_amdgcn_mfma_f32_16x16x32_bf16(aF, bF, acc[tt], 0, 0, 0);
            }
        } else {
            #pragma unroll
            for (int tt = 24; tt < 32; ++tt){
                bf16x8 bF = *reinterpret_cast<const bf16x8*>(&Bs[(tt*16 + l15)*BSTR + l4*8]);
                acc[tt] = __builtin_amdgcn_mfma_f32_16x16x32_bf16(aF, bF, acc[tt], 0, 0, 0);
            }
        }
    }

    const int rowb = n0 + wid*16 + l4*4;
    #pragma unroll
    for (int j = 0; j < 8; ++j){
        int col = j*16 + l15;
        float br  = b_ih[col]       + b_hh[col];
        float bz  = b_ih[128 + col] + b_hh[128 + col];
        float bin = b_ih[256 + col];
        float bhn = b_hh[256 + col];
        #pragma unroll
        for (int rg = 0; rg < 4; ++rg){
            int row = rowb + rg;
            float r   = 1.f/(1.f + __expf(-(acc[j][rg]     + br)));
            float z   = 1.f/(1.f + __expf(-(acc[8+j][rg]   + bz)));
            float nn_ = tanhf(acc[16+j][rg] + bin + r*(acc[24+j][rg] + bhn));
            float hold = h[(size_t)row*H + col];
            float hnew = (1.f - z)*nn_ + z*hold;
            h [(size_t)row*H + col] = hnew;
            hb[(size_t)row*H + col] = f2bf(hnew);
        }
    }
}

// ---------------- pooling ----------------

__global__ __launch_bounds__(128) void pool_kernel(const float* __restrict__ h,
                                                   const int* __restrict__ batch_b, const int* __restrict__ batch_v,
                                                   float* __restrict__ pool){
    int j  = threadIdx.x;
    int n0 = blockIdx.x * 32;
    bool voro = (n0 >= N_NODES);
    int colbase = voro ? 128 : 0;
    int gcur = -1; float acc = 0.f;
    for (int r = 0; r < 32; ++r){
        int node = n0 + r;
        int g = voro ? batch_v[node - N_NODES] : batch_b[node];
        if (g != gcur){
            if (gcur >= 0) atomicAdd(&pool[gcur*256 + colbase + j], acc);
            acc = 0.f; gcur = g;
        }
        acc += fmaxf(h[(size_t)node*H + j], 0.f);
    }
    if (gcur >= 0) atomicAdd(&pool[gcur*256 + colbase + j], acc);
}

__global__ __launch_bounds__(256) void cnt_kernel(const int* __restrict__ batch_b, const int* __restrict__ batch_v,
                                                  int* __restrict__ cnt){
    __shared__ int bins[128];
    int t = threadIdx.x;
    if (t < 128) bins[t] = 0;
    __syncthreads();
    int i = blockIdx.x*256 + t;
    if (i < NN){
        int g = (i < N_NODES) ? batch_b[i] : 64 + batch_v[i - N_NODES];
        atomicAdd(&bins[g], 1);
    }
    __syncthreads();
    if (t < 128 && bins[t] > 0) atomicAdd(&cnt[t], bins[t]);
}

// ---------------- output head ----------------

__global__ __launch_bounds__(256) void head_kernel(const float* __restrict__ pool, const int* __restrict__ cnt,
                                                   const float* __restrict__ W1, const float* __restrict__ b1,
                                                   const float* __restrict__ W2, const float* __restrict__ b2,
                                                   float* __restrict__ out){
    __shared__ float gs[256];
    __shared__ float wsum[4];
    int b = blockIdx.x, j = threadIdx.x;
    int c = (j < 128) ? cnt[b] : cnt[64 + b];
    float denom = (float)((c > 1) ? c : 1);
    gs[j] = pool[b*256 + j] / denom;
    __syncthreads();
    float acc = b1[j];
    for (int k = 0; k < 256; ++k) acc = fmaf(gs[k], W1[k*256 + j], acc);
    float y = fmaxf(acc, 0.f) * W2[j];
    #pragma unroll
    for (int off = 32; off > 0; off >>= 1) y += __shfl_down(y, off, 64);
    if ((j & 63) == 0) wsum[j >> 6] = y;
    __syncthreads();
    if (j == 0){
        float x = wsum[0] + wsum[1] + wsum[2] + wsum[3] + b2[0];
        float sp = (x > 0.f) ? x + log1pf(expf(-x)) : log1pf(expf(x));
        out[b] = sp;
    }
}

// ---------------- launch ----------------

extern "C" void kernel_launch(void* const* d_in, const int* in_sizes, int n_in,
                              void* d_out, int out_size, void* d_ws, size_t ws_size,
                              hipStream_t stream){
    const float* x_b      = (const float*)d_in[0];
    const int*   eib      = (const int*)  d_in[1];
    const int*   batch_b  = (const int*)  d_in[2];
    const float* x_v      = (const float*)d_in[3];
    const int*   eiv      = (const int*)  d_in[4];
    const int*   batch_v  = (const int*)  d_in[5];
    const float* W_emb_b  = (const float*)d_in[6];
    const float* W_emb_v  = (const float*)d_in[7];
    const float* ggc_w    = (const float*)d_in[8];
    const float* gru_w_ih = (const float*)d_in[9];
    const float* gru_w_hh = (const float*)d_in[10];
    const float* gru_b_ih = (const float*)d_in[11];
    const float* gru_b_hh = (const float*)d_in[12];
    const float* W1       = (const float*)d_in[13];
    const float* b1       = (const float*)d_in[14];
    const float* W2       = (const float*)d_in[15];
    const float* b2       = (const float*)d_in[16];
    float* out = (float*)d_out;

    char* ws = (char*)d_ws;
    size_t off = 0;
    auto alloc = [&](size_t bytes)->char*{
        char* p = ws + off; off += (bytes + 255)/256*256; return p;
    };
    float* h        = (float*) alloc((size_t)NN*H*4);        // 102.4 MB
    u16*   hb       = (u16*)   alloc((size_t)NN*H*2);        //  51.2 MB
    u16*   aggb     = (u16*)   alloc((size_t)NN*H*2);        //  51.2 MB
    u16*   m        = (u16*)   alloc((size_t)NN*H*2);        //  51.2 MB
    u16*   Wg_pack  = (u16*)   alloc((size_t)STEPS*4*H*32*2);
    u16*   Wcat     = (u16*)   alloc((size_t)8*512*32*2);
    int*   row_ptr  = (int*)   alloc((size_t)(NN+1)*4);
    int*   deg      = (int*)   alloc((size_t)NNP*4);         // padded for int4 scan
    int*   cursor   = (int*)   alloc((size_t)NN*4);
    int*   csr_src  = (int*)   alloc((size_t)EE*4);
    int*   bsum     = (int*)   alloc((size_t)256*4);
    int*   boff     = (int*)   alloc((size_t)256*4);
    float* pool     = (float*) alloc((size_t)NG*2*H*4);
    int*   cnt      = (int*)   alloc((size_t)2*NG*4);
    (void)ws_size; (void)in_sizes; (void)n_in; (void)out_size;

    hipMemsetAsync(deg,  0, (size_t)NNP*4, stream);
    hipMemsetAsync(pool, 0, (size_t)NG*2*H*4, stream);
    hipMemsetAsync(cnt,  0, (size_t)2*NG*4, stream);

    deg_kernel        <<<(EE + 255)/256, 256, 0, stream>>>(eib, eiv, deg);
    bsum_kernel       <<<NBLK, 256, 0, stream>>>(deg, bsum);
    bscan_kernel      <<<1, 256, 0, stream>>>(bsum, boff);
    scan_final_kernel <<<NBLK, 256, 0, stream>>>(deg, boff, row_ptr, cursor);
    csr_fill_kernel   <<<(EE + 255)/256, 256, 0, stream>>>(eib, eiv, cursor, csr_src);
    prep_weights_kernel<<<512, 256, 0, stream>>>(ggc_w, gru_w_ih, gru_w_hh, Wg_pack, Wcat);

    emb_kernel<<<NN/8, 128, 0, stream>>>(x_b, x_v, W_emb_b, W_emb_v, h, hb);

    for (int s = 0; s < STEPS; ++s){
        mgemm_mfma_kernel<<<NN/64, 256, 0, stream>>>(hb, Wg_pack + (size_t)s*4*H*32, m);
        agg_kernel       <<<NN/4, 256, 0, stream>>>(m, row_ptr, csr_src, aggb);
        gru_mfma_kernel  <<<NN/64, 256, 0, stream>>>(aggb, hb, h, Wcat, gru_b_ih, gru_b_hh);
    }

    pool_kernel<<<NN/32, 128, 0, stream>>>(h, batch_b, batch_v, pool);
    cnt_kernel <<<(NN + 255)/256, 256, 0, stream>>>(batch_b, batch_v, cnt);
    head_kernel<<<NG, 256, 0, stream>>>(pool, cnt, W1, b1, W2, b2, out);
}

// Round 4
// 1180.288 us; speedup vs baseline: 3.8504x; 1.5979x over previous
//
#include <hip/hip_runtime.h>
#include <hip/hip_bf16.h>
#include <math.h>

#define N_NODES   100000
#define N_EDGES   600000
#define NG        64
#define H         128
#define STEPS     4
#define FB        90
#define FV        20
#define NN        (2*N_NODES)   /* 200000 combined nodes */
#define EE        (2*N_EDGES)   /* 1200000 combined edges */
#define BSTR      40            /* LDS row stride in shorts for A tiles */
#define NBLK      196           /* scan blocks: 196*1024 = 200704 >= NN */
#define NNP       (NBLK*1024)   /* padded degree array length */

#define WCAT_KC   (12*64*8)       /* shorts per (s,b1,kc) fragment chunk = 6144 (12KB) */
#define WCAT_HALF (8*WCAT_KC)     /* per (s,b1) */
#define WCAT_STEP (2*WCAT_HALF)   /* per step  */

typedef unsigned short u16;
typedef __attribute__((ext_vector_type(8))) __bf16 bf16x8;
typedef __attribute__((ext_vector_type(4))) float  floatx4;

static __device__ __forceinline__ float bf16_lo(unsigned u){ return __uint_as_float(u << 16); }
static __device__ __forceinline__ float bf16_hi(unsigned u){ return __uint_as_float(u & 0xffff0000u); }
static __device__ __forceinline__ u16 f2bf(float f){
    union { float f; unsigned u; } v; v.f = f;
    unsigned r = v.u + 0x7fffu + ((v.u >> 16) & 1u);
    return (u16)(r >> 16);
}

// ---------------- CSR construction ----------------

__global__ void deg_kernel(const int* __restrict__ eib, const int* __restrict__ eiv,
                           int* __restrict__ deg){
    int e = blockIdx.x*blockDim.x + threadIdx.x;
    if (e >= EE) return;
    int d;
    if (e < N_EDGES) d = eib[N_EDGES + e];
    else             d = eiv[N_EDGES + (e - N_EDGES)] + N_NODES;
    atomicAdd(&deg[d], 1);
}

__global__ __launch_bounds__(256) void bsum_kernel(const int* __restrict__ deg, int* __restrict__ bsum){
    int t = threadIdx.x;
    int4 v = reinterpret_cast<const int4*>(deg)[blockIdx.x*256 + t];
    int s = v.x + v.y + v.z + v.w;
    __shared__ int ss[256];
    ss[t] = s; __syncthreads();
    for (int off = 128; off > 0; off >>= 1){ if (t < off) ss[t] += ss[t + off]; __syncthreads(); }
    if (t == 0) bsum[blockIdx.x] = ss[0];
}

__global__ __launch_bounds__(256) void bscan_kernel(const int* __restrict__ bsum, int* __restrict__ boff){
    int t = threadIdx.x;
    int v = (t < NBLK) ? bsum[t] : 0;
    __shared__ int ss[256];
    ss[t] = v; __syncthreads();
    for (int off = 1; off < 256; off <<= 1){
        int u = (t >= off) ? ss[t - off] : 0;
        __syncthreads();
        ss[t] += u;
        __syncthreads();
    }
    boff[t] = ss[t] - v;   // exclusive
}

__global__ __launch_bounds__(256) void scan_final_kernel(const int* __restrict__ deg, const int* __restrict__ boff,
                                                         int* __restrict__ row_ptr, int* __restrict__ cursor){
    int t = threadIdx.x, b = blockIdx.x;
    int4 v = reinterpret_cast<const int4*>(deg)[b*256 + t];
    int s = v.x + v.y + v.z + v.w;
    __shared__ int ss[256];
    ss[t] = s; __syncthreads();
    for (int off = 1; off < 256; off <<= 1){
        int u = (t >= off) ? ss[t - off] : 0;
        __syncthreads();
        ss[t] += u;
        __syncthreads();
    }
    int base = boff[b] + ss[t] - s;
    int i0 = b*1024 + t*4;
    int e0 = base, e1 = e0 + v.x, e2 = e1 + v.y, e3 = e2 + v.z;
    if (i0 < NN){
        int4 w = make_int4(e0, e1, e2, e3);
        reinterpret_cast<int4*>(row_ptr)[i0 >> 2] = w;
        reinterpret_cast<int4*>(cursor)[i0 >> 2]  = w;
    }
    if (b == 0 && t == 0) row_ptr[NN] = EE;
}

__global__ void csr_fill_kernel(const int* __restrict__ eib, const int* __restrict__ eiv,
                                int* __restrict__ cursor, int* __restrict__ csr_src){
    int e = blockIdx.x*blockDim.x + threadIdx.x;
    if (e >= EE) return;
    int s, d;
    if (e < N_EDGES){ s = eib[e];                 d = eib[N_EDGES + e]; }
    else { int e2 = e - N_EDGES; s = eiv[e2] + N_NODES; d = eiv[N_EDGES + e2] + N_NODES; }
    int pos = atomicAdd(&cursor[d], 1);
    csr_src[pos] = s;
}

// ---------------- weight prep ----------------
// Fold the GGC weight into the GRU input weights (linearity of segment_sum):
//   Bfold[s][k][c] = sum_q Wg[s][k][q] * w_ih[c][q],  k in [0,128), c in [0,384)
__global__ __launch_bounds__(128) void fold_kernel(const float* __restrict__ ggc_w,
                                                   const float* __restrict__ w_ih,
                                                   float* __restrict__ Bfold){
    int blk = blockIdx.x;              // s*128 + k
    int s = blk >> 7, k = blk & 127;
    __shared__ float wg[128];
    int t = threadIdx.x;
    wg[t] = ggc_w[(size_t)s*H*H + (size_t)k*H + t];
    __syncthreads();
    for (int c = t; c < 384; c += 128){
        const float* wr = w_ih + (size_t)c*H;
        float acc = 0.f;
        for (int q = 0; q < 128; q += 4){
            float4 a = *reinterpret_cast<const float4*>(&wg[q]);
            float4 b = *reinterpret_cast<const float4*>(&wr[q]);
            acc += a.x*b.x + a.y*b.y + a.z*b.z + a.w*b.w;
        }
        Bfold[((size_t)s*H + k)*384 + c] = acc;
    }
}

// Pack B into fragment-major layout: Wcat[s][b1][kc][t(12)][lane(64)][v(8)]
//   tile t: gate g=t>>2 (0=r,1=z,2=n), jj=t&3; out col c = (4*b1+jj)*16 + (lane&15)
//   k = kc*32 + (lane>>4)*8 + v.  k<128: from Bfold (agg side); k>=128: from w_hh (h side).
//   n-gate: kc<4 -> i_n (Bfold col 256+c); kc>=4 -> h_n (w_hh row 256+c).
__global__ void pack_kernel(const float* __restrict__ Bfold, const float* __restrict__ w_hh,
                            u16* __restrict__ Wcat){
    int idx = blockIdx.x*256 + threadIdx.x;
    if (idx >= STEPS*WCAT_STEP) return;
    int v    = idx & 7;
    int lane = (idx >> 3) & 63;
    int t    = (idx >> 9) % 12;
    int rem  = idx / (512*12);          // s*16 + b1*8 + kc
    int kc   = rem & 7;
    int b1   = (rem >> 3) & 1;
    int s    = rem >> 4;
    int col16 = lane & 15, l4 = lane >> 4;
    int k = kc*32 + l4*8 + v;
    int g = t >> 2, jj = t & 3;
    int c = (4*b1 + jj)*16 + col16;
    int gc = (g == 2) ? (256 + c) : (g*128 + c);
    float val;
    if (k < 128) val = Bfold[((size_t)s*H + k)*384 + gc];
    else         val = w_hh[(size_t)gc*H + (k - 128)];
    Wcat[idx] = f2bf(val);
}

// ---------------- embedding: h = relu(x @ W_emb), fp32 + bf16 ----------------

__global__ __launch_bounds__(128) void emb_kernel(const float* __restrict__ xb, const float* __restrict__ xv,
                                                  const float* __restrict__ Wb, const float* __restrict__ Wv,
                                                  float* __restrict__ h, u16* __restrict__ hb){
    __shared__ float xs[8][FB];
    int j = threadIdx.x;
    int n0 = blockIdx.x * 8;
    const float* x; const float* W; int K; int xoff;
    if (n0 < N_NODES){ x = xb; W = Wb; K = FB; xoff = n0; }
    else             { x = xv; W = Wv; K = FV; xoff = n0 - N_NODES; }
    for (int i = j; i < 8*K; i += 128){ int r = i / K, c = i - r*K; xs[r][c] = x[(xoff + r)*K + c]; }
    __syncthreads();
    float acc[8];
    #pragma unroll
    for (int n = 0; n < 8; ++n) acc[n] = 0.f;
    for (int k = 0; k < K; ++k){
        float w = W[k*H + j];
        #pragma unroll
        for (int n = 0; n < 8; ++n) acc[n] = fmaf(xs[n][k], w, acc[n]);
    }
    #pragma unroll
    for (int n = 0; n < 8; ++n){
        float v = fmaxf(acc[n], 0.f);
        h [(size_t)(n0 + n)*H + j] = v;
        hb[(size_t)(n0 + n)*H + j] = f2bf(v);
    }
}

// ---------------- agg_raw[dst] = sum hb[src]  (bf16 in, bf16 out, 2-edge ILP) ----------------

__global__ __launch_bounds__(256) void agg_kernel(const u16* __restrict__ hb,
                                                  const int* __restrict__ row_ptr,
                                                  const int* __restrict__ csr_src,
                                                  u16* __restrict__ aggb){
    int wid  = threadIdx.x >> 6;
    int lane = threadIdx.x & 63;
    int node = blockIdx.x*4 + wid;
    int beg = row_ptr[node], end = row_ptr[node+1];
    float a0 = 0.f, a1 = 0.f, c0 = 0.f, c1 = 0.f;
    const unsigned* mbase = reinterpret_cast<const unsigned*>(hb);
    int e = beg;
    for (; e + 1 < end; e += 2){
        int s0 = csr_src[e], s1 = csr_src[e+1];
        unsigned u0 = mbase[(size_t)s0*(H/2) + lane];
        unsigned u1 = mbase[(size_t)s1*(H/2) + lane];
        a0 += bf16_lo(u0); a1 += bf16_hi(u0);
        c0 += bf16_lo(u1); c1 += bf16_hi(u1);
    }
    if (e < end){
        int s0 = csr_src[e];
        unsigned u0 = mbase[(size_t)s0*(H/2) + lane];
        a0 += bf16_lo(u0); a1 += bf16_hi(u0);
    }
    a0 += c0; a1 += c1;
    unsigned lo = f2bf(a0), hi = f2bf(a1);
    reinterpret_cast<unsigned*>(aggb)[(size_t)node*(H/2) + lane] = (hi << 16) | lo;
}

// ---------------- fused GRU via MFMA (folded weights, N-split, fragment-major B) ----------------
// grid (NN/64, 2). Block: 64 rows x 256 B-cols (its 4 c-tiles x {r,z,n}).
// Wave w: rows n0+16w..+15. Acc: accR/accZ/accNi/accNh[4] = 16 tiles = 64 AGPR.
// K=256 (kc 0..7): kc<4 A=aggb (folded agg weights), kc>=4 A=hb_in (w_hh).
// hb ping-pong avoids the cross-block A-read race; fp32 h updated in place (disjoint cols).

__global__ __launch_bounds__(256, 3) void gru_mfma_kernel(const u16* __restrict__ aggb,
                                                          const u16* __restrict__ hb_in,
                                                          u16* __restrict__ hb_out,
                                                          float* __restrict__ h,
                                                          const u16* __restrict__ Wcat,  /* this step: [2][8][12][64][8] */
                                                          const float* __restrict__ b_ih,
                                                          const float* __restrict__ b_hh){
    __shared__ u16 Bs[WCAT_KC];      // 12 KB, fragment-major
    __shared__ u16 As[64*BSTR];      // 5 KB
    const int t = threadIdx.x;
    const int wid = t >> 6, lane = t & 63;
    const int l15 = lane & 15, l4 = lane >> 4;
    const int n0 = blockIdx.x * 64;
    const int b1 = blockIdx.y;
    const u16* Wsrc = Wcat + (size_t)b1*WCAT_HALF;

    floatx4 accR[4], accZ[4], accNi[4], accNh[4];
    #pragma unroll
    for (int i = 0; i < 4; ++i){
        accR[i] = (floatx4){0.f,0.f,0.f,0.f};  accZ[i]  = (floatx4){0.f,0.f,0.f,0.f};
        accNi[i] = (floatx4){0.f,0.f,0.f,0.f}; accNh[i] = (floatx4){0.f,0.f,0.f,0.f};
    }

    for (int kc = 0; kc < 8; ++kc){
        __syncthreads();
        {   // stage B: 768 int4, fragment-major -> fully coalesced, conflict-free
            const u16* src = Wsrc + (size_t)kc*WCAT_KC;
            #pragma unroll
            for (int p = 0; p < 3; ++p){
                int i = t + p*256;
                *reinterpret_cast<int4*>(&Bs[i*8]) = *reinterpret_cast<const int4*>(src + (size_t)i*8);
            }
        }
        {   // stage A: 64 rows x 32 shorts
            int row = t >> 2, part = t & 3;
            const u16* srcA = (kc < 4) ? aggb : hb_in;
            const int4 v = *reinterpret_cast<const int4*>(srcA + (size_t)(n0 + row)*H + (kc & 3)*32 + part*8);
            *reinterpret_cast<int4*>(&As[row*BSTR + part*8]) = v;
        }
        __syncthreads();
        bf16x8 aF = *reinterpret_cast<const bf16x8*>(&As[(wid*16 + l15)*BSTR + l4*8]);
        if (kc < 4){
            #pragma unroll
            for (int j = 0; j < 4; ++j){
                bf16x8 bR = *reinterpret_cast<const bf16x8*>(&Bs[((0*4 + j)*64 + lane)*8]);
                bf16x8 bZ = *reinterpret_cast<const bf16x8*>(&Bs[((1*4 + j)*64 + lane)*8]);
                bf16x8 bN = *reinterpret_cast<const bf16x8*>(&Bs[((2*4 + j)*64 + lane)*8]);
                accR[j]  = __builtin_amdgcn_mfma_f32_16x16x32_bf16(aF, bR, accR[j], 0, 0, 0);
                accZ[j]  = __builtin_amdgcn_mfma_f32_16x16x32_bf16(aF, bZ, accZ[j], 0, 0, 0);
                accNi[j] = __builtin_amdgcn_mfma_f32_16x16x32_bf16(aF, bN, accNi[j], 0, 0, 0);
            }
        } else {
            #pragma unroll
            for (int j = 0; j < 4; ++j){
                bf16x8 bR = *reinterpret_cast<const bf16x8*>(&Bs[((0*4 + j)*64 + lane)*8]);
                bf16x8 bZ = *reinterpret_cast<const bf16x8*>(&Bs[((1*4 + j)*64 + lane)*8]);
                bf16x8 bN = *reinterpret_cast<const bf16x8*>(&Bs[((2*4 + j)*64 + lane)*8]);
                accR[j]  = __builtin_amdgcn_mfma_f32_16x16x32_bf16(aF, bR, accR[j], 0, 0, 0);
                accZ[j]  = __builtin_amdgcn_mfma_f32_16x16x32_bf16(aF, bZ, accZ[j], 0, 0, 0);
                accNh[j] = __builtin_amdgcn_mfma_f32_16x16x32_bf16(aF, bN, accNh[j], 0, 0, 0);
            }
        }
    }

    const int rowb = n0 + wid*16 + l4*4;
    #pragma unroll
    for (int jj = 0; jj < 4; ++jj){
        int col = (4*b1 + jj)*16 + l15;
        float br  = b_ih[col]       + b_hh[col];
        float bz  = b_ih[128 + col] + b_hh[128 + col];
        float bin = b_ih[256 + col];
        float bhn = b_hh[256 + col];
        #pragma unroll
        for (int rg = 0; rg < 4; ++rg){
            int row = rowb + rg;
            float r   = 1.f/(1.f + __expf(-(accR[jj][rg] + br)));
            float z   = 1.f/(1.f + __expf(-(accZ[jj][rg] + bz)));
            float nn_ = tanhf(accNi[jj][rg] + bin + r*(accNh[jj][rg] + bhn));
            float hold = h[(size_t)row*H + col];
            float hnew = (1.f - z)*nn_ + z*hold;
            h     [(size_t)row*H + col] = hnew;
            hb_out[(size_t)row*H + col] = f2bf(hnew);
        }
    }
}

// ---------------- pooling ----------------

__global__ __launch_bounds__(128) void pool_kernel(const float* __restrict__ h,
                                                   const int* __restrict__ batch_b, const int* __restrict__ batch_v,
                                                   float* __restrict__ pool){
    int j  = threadIdx.x;
    int n0 = blockIdx.x * 32;
    bool voro = (n0 >= N_NODES);
    int colbase = voro ? 128 : 0;
    int gcur = -1; float acc = 0.f;
    for (int r = 0; r < 32; ++r){
        int node = n0 + r;
        int g = voro ? batch_v[node - N_NODES] : batch_b[node];
        if (g != gcur){
            if (gcur >= 0) atomicAdd(&pool[gcur*256 + colbase + j], acc);
            acc = 0.f; gcur = g;
        }
        acc += fmaxf(h[(size_t)node*H + j], 0.f);
    }
    if (gcur >= 0) atomicAdd(&pool[gcur*256 + colbase + j], acc);
}

__global__ __launch_bounds__(256) void cnt_kernel(const int* __restrict__ batch_b, const int* __restrict__ batch_v,
                                                  int* __restrict__ cnt){
    __shared__ int bins[128];
    int t = threadIdx.x;
    if (t < 128) bins[t] = 0;
    __syncthreads();
    int i = blockIdx.x*256 + t;
    if (i < NN){
        int g = (i < N_NODES) ? batch_b[i] : 64 + batch_v[i - N_NODES];
        atomicAdd(&bins[g], 1);
    }
    __syncthreads();
    if (t < 128 && bins[t] > 0) atomicAdd(&cnt[t], bins[t]);
}

// ---------------- output head ----------------

__global__ __launch_bounds__(256) void head_kernel(const float* __restrict__ pool, const int* __restrict__ cnt,
                                                   const float* __restrict__ W1, const float* __restrict__ b1,
                                                   const float* __restrict__ W2, const float* __restrict__ b2,
                                                   float* __restrict__ out){
    __shared__ float gs[256];
    __shared__ float wsum[4];
    int b = blockIdx.x, j = threadIdx.x;
    int c = (j < 128) ? cnt[b] : cnt[64 + b];
    float denom = (float)((c > 1) ? c : 1);
    gs[j] = pool[b*256 + j] / denom;
    __syncthreads();
    float acc = b1[j];
    for (int k = 0; k < 256; ++k) acc = fmaf(gs[k], W1[k*256 + j], acc);
    float y = fmaxf(acc, 0.f) * W2[j];
    #pragma unroll
    for (int off = 32; off > 0; off >>= 1) y += __shfl_down(y, off, 64);
    if ((j & 63) == 0) wsum[j >> 6] = y;
    __syncthreads();
    if (j == 0){
        float x = wsum[0] + wsum[1] + wsum[2] + wsum[3] + b2[0];
        float sp = (x > 0.f) ? x + log1pf(expf(-x)) : log1pf(expf(x));
        out[b] = sp;
    }
}

// ---------------- launch ----------------

extern "C" void kernel_launch(void* const* d_in, const int* in_sizes, int n_in,
                              void* d_out, int out_size, void* d_ws, size_t ws_size,
                              hipStream_t stream){
    const float* x_b      = (const float*)d_in[0];
    const int*   eib      = (const int*)  d_in[1];
    const int*   batch_b  = (const int*)  d_in[2];
    const float* x_v      = (const float*)d_in[3];
    const int*   eiv      = (const int*)  d_in[4];
    const int*   batch_v  = (const int*)  d_in[5];
    const float* W_emb_b  = (const float*)d_in[6];
    const float* W_emb_v  = (const float*)d_in[7];
    const float* ggc_w    = (const float*)d_in[8];
    const float* gru_w_ih = (const float*)d_in[9];
    const float* gru_w_hh = (const float*)d_in[10];
    const float* gru_b_ih = (const float*)d_in[11];
    const float* gru_b_hh = (const float*)d_in[12];
    const float* W1       = (const float*)d_in[13];
    const float* b1       = (const float*)d_in[14];
    const float* W2       = (const float*)d_in[15];
    const float* b2       = (const float*)d_in[16];
    float* out = (float*)d_out;

    char* ws = (char*)d_ws;
    size_t off = 0;
    auto alloc = [&](size_t bytes)->char*{
        char* p = ws + off; off += (bytes + 255)/256*256; return p;
    };
    float* h        = (float*) alloc((size_t)NN*H*4);        // 102.4 MB
    u16*   hb0      = (u16*)   alloc((size_t)NN*H*2);        //  51.2 MB
    u16*   hb1      = (u16*)   alloc((size_t)NN*H*2);        //  51.2 MB
    u16*   aggb     = (u16*)   alloc((size_t)NN*H*2);        //  51.2 MB
    float* Bfold    = (float*) alloc((size_t)STEPS*H*384*4); // 786 KB
    u16*   Wcat     = (u16*)   alloc((size_t)STEPS*WCAT_STEP*2);
    int*   row_ptr  = (int*)   alloc((size_t)(NN+1)*4);
    int*   deg      = (int*)   alloc((size_t)NNP*4);
    int*   cursor   = (int*)   alloc((size_t)NN*4);
    int*   csr_src  = (int*)   alloc((size_t)EE*4);
    int*   bsum     = (int*)   alloc((size_t)256*4);
    int*   boff     = (int*)   alloc((size_t)256*4);
    float* pool     = (float*) alloc((size_t)NG*2*H*4);
    int*   cnt      = (int*)   alloc((size_t)2*NG*4);
    (void)ws_size; (void)in_sizes; (void)n_in; (void)out_size;

    hipMemsetAsync(deg,  0, (size_t)NNP*4, stream);
    hipMemsetAsync(pool, 0, (size_t)NG*2*H*4, stream);
    hipMemsetAsync(cnt,  0, (size_t)2*NG*4, stream);

    deg_kernel        <<<(EE + 255)/256, 256, 0, stream>>>(eib, eiv, deg);
    bsum_kernel       <<<NBLK, 256, 0, stream>>>(deg, bsum);
    bscan_kernel      <<<1, 256, 0, stream>>>(bsum, boff);
    scan_final_kernel <<<NBLK, 256, 0, stream>>>(deg, boff, row_ptr, cursor);
    csr_fill_kernel   <<<(EE + 255)/256, 256, 0, stream>>>(eib, eiv, cursor, csr_src);
    fold_kernel       <<<STEPS*H, 128, 0, stream>>>(ggc_w, gru_w_ih, Bfold);
    pack_kernel       <<<(STEPS*WCAT_STEP + 255)/256, 256, 0, stream>>>(Bfold, gru_w_hh, Wcat);

    emb_kernel<<<NN/8, 128, 0, stream>>>(x_b, x_v, W_emb_b, W_emb_v, h, hb0);

    u16* hbs[2] = { hb0, hb1 };
    for (int s = 0; s < STEPS; ++s){
        u16* hin  = hbs[s & 1];
        u16* hout = hbs[(s + 1) & 1];
        agg_kernel     <<<NN/4, 256, 0, stream>>>(hin, row_ptr, csr_src, aggb);
        gru_mfma_kernel<<<dim3(NN/64, 2), 256, 0, stream>>>(aggb, hin, hout, h,
                                                            Wcat + (size_t)s*WCAT_STEP,
                                                            gru_b_ih, gru_b_hh);
    }

    pool_kernel<<<NN/32, 128, 0, stream>>>(h, batch_b, batch_v, pool);
    cnt_kernel <<<(NN + 255)/256, 256, 0, stream>>>(batch_b, batch_v, cnt);
    head_kernel<<<NG, 256, 0, stream>>>(pool, cnt, W1, b1, W2, b2, out);
}

// Round 5
// 1056.236 us; speedup vs baseline: 4.3026x; 1.1174x over previous
//
#include <hip/hip_runtime.h>
#include <hip/hip_bf16.h>
#include <math.h>

#define N_NODES   100000
#define N_EDGES   600000
#define NG        64
#define H         128
#define STEPS     4
#define FB        90
#define FV        20
#define NN        (2*N_NODES)   /* 200000 combined nodes */
#define EE        (2*N_EDGES)   /* 1200000 combined edges */
#define BSTR      40            /* LDS row stride in shorts for A tiles */
#define NBLK      196           /* scan blocks: 196*1024 = 200704 >= NN */
#define NNP       (NBLK*1024)   /* padded degree array length */

#define WCAT_KC   (12*64*8)       /* shorts per (s,b1,kc) fragment chunk = 6144 (12KB) */
#define WCAT_HALF (8*WCAT_KC)     /* per (s,b1) */
#define WCAT_STEP (2*WCAT_HALF)   /* per step  */

typedef unsigned short u16;
typedef __attribute__((ext_vector_type(8))) __bf16 bf16x8;
typedef __attribute__((ext_vector_type(4))) float  floatx4;

static __device__ __forceinline__ float bf16_lo(unsigned u){ return __uint_as_float(u << 16); }
static __device__ __forceinline__ float bf16_hi(unsigned u){ return __uint_as_float(u & 0xffff0000u); }
static __device__ __forceinline__ u16 f2bf(float f){
    union { float f; unsigned u; } v; v.f = f;
    unsigned r = v.u + 0x7fffu + ((v.u >> 16) & 1u);
    return (u16)(r >> 16);
}

// ---------------- CSR construction ----------------

__global__ void deg_kernel(const int* __restrict__ eib, const int* __restrict__ eiv,
                           int* __restrict__ deg){
    int e = blockIdx.x*blockDim.x + threadIdx.x;
    if (e >= EE) return;
    int d;
    if (e < N_EDGES) d = eib[N_EDGES + e];
    else             d = eiv[N_EDGES + (e - N_EDGES)] + N_NODES;
    atomicAdd(&deg[d], 1);
}

__global__ __launch_bounds__(256) void bsum_kernel(const int* __restrict__ deg, int* __restrict__ bsum){
    int t = threadIdx.x;
    int4 v = reinterpret_cast<const int4*>(deg)[blockIdx.x*256 + t];
    int s = v.x + v.y + v.z + v.w;
    __shared__ int ss[256];
    ss[t] = s; __syncthreads();
    for (int off = 128; off > 0; off >>= 1){ if (t < off) ss[t] += ss[t + off]; __syncthreads(); }
    if (t == 0) bsum[blockIdx.x] = ss[0];
}

__global__ __launch_bounds__(256) void bscan_kernel(const int* __restrict__ bsum, int* __restrict__ boff){
    int t = threadIdx.x;
    int v = (t < NBLK) ? bsum[t] : 0;
    __shared__ int ss[256];
    ss[t] = v; __syncthreads();
    for (int off = 1; off < 256; off <<= 1){
        int u = (t >= off) ? ss[t - off] : 0;
        __syncthreads();
        ss[t] += u;
        __syncthreads();
    }
    boff[t] = ss[t] - v;   // exclusive
}

__global__ __launch_bounds__(256) void scan_final_kernel(const int* __restrict__ deg, const int* __restrict__ boff,
                                                         int* __restrict__ row_ptr, int* __restrict__ cursor){
    int t = threadIdx.x, b = blockIdx.x;
    int4 v = reinterpret_cast<const int4*>(deg)[b*256 + t];
    int s = v.x + v.y + v.z + v.w;
    __shared__ int ss[256];
    ss[t] = s; __syncthreads();
    for (int off = 1; off < 256; off <<= 1){
        int u = (t >= off) ? ss[t - off] : 0;
        __syncthreads();
        ss[t] += u;
        __syncthreads();
    }
    int base = boff[b] + ss[t] - s;
    int i0 = b*1024 + t*4;
    int e0 = base, e1 = e0 + v.x, e2 = e1 + v.y, e3 = e2 + v.z;
    if (i0 < NN){
        int4 w = make_int4(e0, e1, e2, e3);
        reinterpret_cast<int4*>(row_ptr)[i0 >> 2] = w;
        reinterpret_cast<int4*>(cursor)[i0 >> 2]  = w;
    }
    if (b == 0 && t == 0) row_ptr[NN] = EE;
}

__global__ void csr_fill_kernel(const int* __restrict__ eib, const int* __restrict__ eiv,
                                int* __restrict__ cursor, int* __restrict__ csr_src){
    int e = blockIdx.x*blockDim.x + threadIdx.x;
    if (e >= EE) return;
    int s, d;
    if (e < N_EDGES){ s = eib[e];                 d = eib[N_EDGES + e]; }
    else { int e2 = e - N_EDGES; s = eiv[e2] + N_NODES; d = eiv[N_EDGES + e2] + N_NODES; }
    int pos = atomicAdd(&cursor[d], 1);
    csr_src[pos] = s;
}

// ---------------- weight prep ----------------
// Fold the GGC weight into the GRU input weights (linearity of segment_sum):
//   Bfold[s][k][c] = sum_q Wg[s][k][q] * w_ih[c][q],  k in [0,128), c in [0,384)
__global__ __launch_bounds__(128) void fold_kernel(const float* __restrict__ ggc_w,
                                                   const float* __restrict__ w_ih,
                                                   float* __restrict__ Bfold){
    int blk = blockIdx.x;              // s*128 + k
    int s = blk >> 7, k = blk & 127;
    __shared__ float wg[128];
    int t = threadIdx.x;
    wg[t] = ggc_w[(size_t)s*H*H + (size_t)k*H + t];
    __syncthreads();
    for (int c = t; c < 384; c += 128){
        const float* wr = w_ih + (size_t)c*H;
        float acc = 0.f;
        for (int q = 0; q < 128; q += 4){
            float4 a = *reinterpret_cast<const float4*>(&wg[q]);
            float4 b = *reinterpret_cast<const float4*>(&wr[q]);
            acc += a.x*b.x + a.y*b.y + a.z*b.z + a.w*b.w;
        }
        Bfold[((size_t)s*H + k)*384 + c] = acc;
    }
}

// Pack B into fragment-major layout: Wcat[s][b1][kc][t(12)][lane(64)][v(8)]
__global__ void pack_kernel(const float* __restrict__ Bfold, const float* __restrict__ w_hh,
                            u16* __restrict__ Wcat){
    int idx = blockIdx.x*256 + threadIdx.x;
    if (idx >= STEPS*WCAT_STEP) return;
    int v    = idx & 7;
    int lane = (idx >> 3) & 63;
    int t    = (idx >> 9) % 12;
    int rem  = idx / (512*12);          // s*16 + b1*8 + kc
    int kc   = rem & 7;
    int b1   = (rem >> 3) & 1;
    int s    = rem >> 4;
    int col16 = lane & 15, l4 = lane >> 4;
    int k = kc*32 + l4*8 + v;
    int g = t >> 2, jj = t & 3;
    int c = (4*b1 + jj)*16 + col16;
    int gc = (g == 2) ? (256 + c) : (g*128 + c);
    float val;
    if (k < 128) val = Bfold[((size_t)s*H + k)*384 + gc];
    else         val = w_hh[(size_t)gc*H + (k - 128)];
    Wcat[idx] = f2bf(val);
}

// ---------------- embedding: hb = bf16(relu(x @ W_emb)) ----------------

__global__ __launch_bounds__(128) void emb_kernel(const float* __restrict__ xb, const float* __restrict__ xv,
                                                  const float* __restrict__ Wb, const float* __restrict__ Wv,
                                                  u16* __restrict__ hb){
    __shared__ float xs[8][FB];
    int j = threadIdx.x;
    int n0 = blockIdx.x * 8;
    const float* x; const float* W; int K; int xoff;
    if (n0 < N_NODES){ x = xb; W = Wb; K = FB; xoff = n0; }
    else             { x = xv; W = Wv; K = FV; xoff = n0 - N_NODES; }
    for (int i = j; i < 8*K; i += 128){ int r = i / K, c = i - r*K; xs[r][c] = x[(xoff + r)*K + c]; }
    __syncthreads();
    float acc[8];
    #pragma unroll
    for (int n = 0; n < 8; ++n) acc[n] = 0.f;
    for (int k = 0; k < K; ++k){
        float w = W[k*H + j];
        #pragma unroll
        for (int n = 0; n < 8; ++n) acc[n] = fmaf(xs[n][k], w, acc[n]);
    }
    #pragma unroll
    for (int n = 0; n < 8; ++n)
        hb[(size_t)(n0 + n)*H + j] = f2bf(fmaxf(acc[n], 0.f));
}

// ---------------- agg_raw[dst] = sum hb[src]  (bf16 in, bf16 out, 2-edge ILP) ----------------

__global__ __launch_bounds__(256) void agg_kernel(const u16* __restrict__ hb,
                                                  const int* __restrict__ row_ptr,
                                                  const int* __restrict__ csr_src,
                                                  u16* __restrict__ aggb){
    int wid  = threadIdx.x >> 6;
    int lane = threadIdx.x & 63;
    int node = blockIdx.x*4 + wid;
    int beg = row_ptr[node], end = row_ptr[node+1];
    float a0 = 0.f, a1 = 0.f, c0 = 0.f, c1 = 0.f;
    const unsigned* mbase = reinterpret_cast<const unsigned*>(hb);
    int e = beg;
    for (; e + 1 < end; e += 2){
        int s0 = csr_src[e], s1 = csr_src[e+1];
        unsigned u0 = mbase[(size_t)s0*(H/2) + lane];
        unsigned u1 = mbase[(size_t)s1*(H/2) + lane];
        a0 += bf16_lo(u0); a1 += bf16_hi(u0);
        c0 += bf16_lo(u1); c1 += bf16_hi(u1);
    }
    if (e < end){
        int s0 = csr_src[e];
        unsigned u0 = mbase[(size_t)s0*(H/2) + lane];
        a0 += bf16_lo(u0); a1 += bf16_hi(u0);
    }
    a0 += c0; a1 += c1;
    unsigned lo = f2bf(a0), hi = f2bf(a1);
    reinterpret_cast<unsigned*>(aggb)[(size_t)node*(H/2) + lane] = (hi << 16) | lo;
}

// ---------------- fused GRU via MFMA (bf16 state, no fp32 master) ----------------
// grid (NN/64, 2). Block: 64 rows x 256 B-cols. 16 acc tiles = 64 AGPR.
// hold read from hb_in (bytes are L2-hot from the kc>=4 A staging).

__global__ __launch_bounds__(256, 3) void gru_mfma_kernel(const u16* __restrict__ aggb,
                                                          const u16* __restrict__ hb_in,
                                                          u16* __restrict__ hb_out,
                                                          const u16* __restrict__ Wcat,  /* this step: [2][8][12][64][8] */
                                                          const float* __restrict__ b_ih,
                                                          const float* __restrict__ b_hh){
    __shared__ u16 Bs[WCAT_KC];      // 12 KB, fragment-major
    __shared__ u16 As[64*BSTR];      // 5 KB
    const int t = threadIdx.x;
    const int wid = t >> 6, lane = t & 63;
    const int l15 = lane & 15, l4 = lane >> 4;
    const int n0 = blockIdx.x * 64;
    const int b1 = blockIdx.y;
    const u16* Wsrc = Wcat + (size_t)b1*WCAT_HALF;

    floatx4 accR[4], accZ[4], accNi[4], accNh[4];
    #pragma unroll
    for (int i = 0; i < 4; ++i){
        accR[i] = (floatx4){0.f,0.f,0.f,0.f};  accZ[i]  = (floatx4){0.f,0.f,0.f,0.f};
        accNi[i] = (floatx4){0.f,0.f,0.f,0.f}; accNh[i] = (floatx4){0.f,0.f,0.f,0.f};
    }

    for (int kc = 0; kc < 8; ++kc){
        __syncthreads();
        {   // stage B: 768 int4, fragment-major -> fully coalesced, conflict-free
            const u16* src = Wsrc + (size_t)kc*WCAT_KC;
            #pragma unroll
            for (int p = 0; p < 3; ++p){
                int i = t + p*256;
                *reinterpret_cast<int4*>(&Bs[i*8]) = *reinterpret_cast<const int4*>(src + (size_t)i*8);
            }
        }
        {   // stage A: 64 rows x 32 shorts
            int row = t >> 2, part = t & 3;
            const u16* srcA = (kc < 4) ? aggb : hb_in;
            const int4 v = *reinterpret_cast<const int4*>(srcA + (size_t)(n0 + row)*H + (kc & 3)*32 + part*8);
            *reinterpret_cast<int4*>(&As[row*BSTR + part*8]) = v;
        }
        __syncthreads();
        bf16x8 aF = *reinterpret_cast<const bf16x8*>(&As[(wid*16 + l15)*BSTR + l4*8]);
        if (kc < 4){
            #pragma unroll
            for (int j = 0; j < 4; ++j){
                bf16x8 bR = *reinterpret_cast<const bf16x8*>(&Bs[((0*4 + j)*64 + lane)*8]);
                bf16x8 bZ = *reinterpret_cast<const bf16x8*>(&Bs[((1*4 + j)*64 + lane)*8]);
                bf16x8 bN = *reinterpret_cast<const bf16x8*>(&Bs[((2*4 + j)*64 + lane)*8]);
                accR[j]  = __builtin_amdgcn_mfma_f32_16x16x32_bf16(aF, bR, accR[j], 0, 0, 0);
                accZ[j]  = __builtin_amdgcn_mfma_f32_16x16x32_bf16(aF, bZ, accZ[j], 0, 0, 0);
                accNi[j] = __builtin_amdgcn_mfma_f32_16x16x32_bf16(aF, bN, accNi[j], 0, 0, 0);
            }
        } else {
            #pragma unroll
            for (int j = 0; j < 4; ++j){
                bf16x8 bR = *reinterpret_cast<const bf16x8*>(&Bs[((0*4 + j)*64 + lane)*8]);
                bf16x8 bZ = *reinterpret_cast<const bf16x8*>(&Bs[((1*4 + j)*64 + lane)*8]);
                bf16x8 bN = *reinterpret_cast<const bf16x8*>(&Bs[((2*4 + j)*64 + lane)*8]);
                accR[j]  = __builtin_amdgcn_mfma_f32_16x16x32_bf16(aF, bR, accR[j], 0, 0, 0);
                accZ[j]  = __builtin_amdgcn_mfma_f32_16x16x32_bf16(aF, bZ, accZ[j], 0, 0, 0);
                accNh[j] = __builtin_amdgcn_mfma_f32_16x16x32_bf16(aF, bN, accNh[j], 0, 0, 0);
            }
        }
    }

    const int rowb = n0 + wid*16 + l4*4;
    #pragma unroll
    for (int jj = 0; jj < 4; ++jj){
        int col = (4*b1 + jj)*16 + l15;
        float br  = b_ih[col]       + b_hh[col];
        float bz  = b_ih[128 + col] + b_hh[128 + col];
        float bin = b_ih[256 + col];
        float bhn = b_hh[256 + col];
        #pragma unroll
        for (int rg = 0; rg < 4; ++rg){
            int row = rowb + rg;
            float r   = 1.f/(1.f + __expf(-(accR[jj][rg] + br)));
            float z   = 1.f/(1.f + __expf(-(accZ[jj][rg] + bz)));
            float nn_ = tanhf(accNi[jj][rg] + bin + r*(accNh[jj][rg] + bhn));
            float hold = bf16_lo((unsigned)hb_in[(size_t)row*H + col]);
            float hnew = (1.f - z)*nn_ + z*hold;
            hb_out[(size_t)row*H + col] = f2bf(hnew);
        }
    }
}

// ---------------- pooling (bf16 state in) ----------------

__global__ __launch_bounds__(128) void pool_kernel(const u16* __restrict__ hb,
                                                   const int* __restrict__ batch_b, const int* __restrict__ batch_v,
                                                   float* __restrict__ pool){
    int j  = threadIdx.x;
    int n0 = blockIdx.x * 32;
    bool voro = (n0 >= N_NODES);
    int colbase = voro ? 128 : 0;
    int gcur = -1; float acc = 0.f;
    for (int r = 0; r < 32; ++r){
        int node = n0 + r;
        int g = voro ? batch_v[node - N_NODES] : batch_b[node];
        if (g != gcur){
            if (gcur >= 0) atomicAdd(&pool[gcur*256 + colbase + j], acc);
            acc = 0.f; gcur = g;
        }
        acc += fmaxf(bf16_lo((unsigned)hb[(size_t)node*H + j]), 0.f);
    }
    if (gcur >= 0) atomicAdd(&pool[gcur*256 + colbase + j], acc);
}

__global__ __launch_bounds__(256) void cnt_kernel(const int* __restrict__ batch_b, const int* __restrict__ batch_v,
                                                  int* __restrict__ cnt){
    __shared__ int bins[128];
    int t = threadIdx.x;
    if (t < 128) bins[t] = 0;
    __syncthreads();
    int i = blockIdx.x*256 + t;
    if (i < NN){
        int g = (i < N_NODES) ? batch_b[i] : 64 + batch_v[i - N_NODES];
        atomicAdd(&bins[g], 1);
    }
    __syncthreads();
    if (t < 128 && bins[t] > 0) atomicAdd(&cnt[t], bins[t]);
}

// ---------------- output head ----------------

__global__ __launch_bounds__(256) void head_kernel(const float* __restrict__ pool, const int* __restrict__ cnt,
                                                   const float* __restrict__ W1, const float* __restrict__ b1,
                                                   const float* __restrict__ W2, const float* __restrict__ b2,
                                                   float* __restrict__ out){
    __shared__ float gs[256];
    __shared__ float wsum[4];
    int b = blockIdx.x, j = threadIdx.x;
    int c = (j < 128) ? cnt[b] : cnt[64 + b];
    float denom = (float)((c > 1) ? c : 1);
    gs[j] = pool[b*256 + j] / denom;
    __syncthreads();
    float acc = b1[j];
    for (int k = 0; k < 256; ++k) acc = fmaf(gs[k], W1[k*256 + j], acc);
    float y = fmaxf(acc, 0.f) * W2[j];
    #pragma unroll
    for (int off = 32; off > 0; off >>= 1) y += __shfl_down(y, off, 64);
    if ((j & 63) == 0) wsum[j >> 6] = y;
    __syncthreads();
    if (j == 0){
        float x = wsum[0] + wsum[1] + wsum[2] + wsum[3] + b2[0];
        float sp = (x > 0.f) ? x + log1pf(expf(-x)) : log1pf(expf(x));
        out[b] = sp;
    }
}

// ---------------- launch ----------------

extern "C" void kernel_launch(void* const* d_in, const int* in_sizes, int n_in,
                              void* d_out, int out_size, void* d_ws, size_t ws_size,
                              hipStream_t stream){
    const float* x_b      = (const float*)d_in[0];
    const int*   eib      = (const int*)  d_in[1];
    const int*   batch_b  = (const int*)  d_in[2];
    const float* x_v      = (const float*)d_in[3];
    const int*   eiv      = (const int*)  d_in[4];
    const int*   batch_v  = (const int*)  d_in[5];
    const float* W_emb_b  = (const float*)d_in[6];
    const float* W_emb_v  = (const float*)d_in[7];
    const float* ggc_w    = (const float*)d_in[8];
    const float* gru_w_ih = (const float*)d_in[9];
    const float* gru_w_hh = (const float*)d_in[10];
    const float* gru_b_ih = (const float*)d_in[11];
    const float* gru_b_hh = (const float*)d_in[12];
    const float* W1       = (const float*)d_in[13];
    const float* b1       = (const float*)d_in[14];
    const float* W2       = (const float*)d_in[15];
    const float* b2       = (const float*)d_in[16];
    float* out = (float*)d_out;

    char* ws = (char*)d_ws;
    size_t off = 0;
    auto alloc = [&](size_t bytes)->char*{
        char* p = ws + off; off += (bytes + 255)/256*256; return p;
    };
    u16*   hb0      = (u16*)   alloc((size_t)NN*H*2);        //  51.2 MB
    u16*   hb1      = (u16*)   alloc((size_t)NN*H*2);        //  51.2 MB
    u16*   aggb     = (u16*)   alloc((size_t)NN*H*2);        //  51.2 MB
    float* Bfold    = (float*) alloc((size_t)STEPS*H*384*4); // 786 KB
    u16*   Wcat     = (u16*)   alloc((size_t)STEPS*WCAT_STEP*2);
    int*   row_ptr  = (int*)   alloc((size_t)(NN+1)*4);
    int*   deg      = (int*)   alloc((size_t)NNP*4);
    int*   cursor   = (int*)   alloc((size_t)NN*4);
    int*   csr_src  = (int*)   alloc((size_t)EE*4);
    int*   bsum     = (int*)   alloc((size_t)256*4);
    int*   boff     = (int*)   alloc((size_t)256*4);
    float* pool     = (float*) alloc((size_t)NG*2*H*4);
    int*   cnt      = (int*)   alloc((size_t)2*NG*4);
    (void)ws_size; (void)in_sizes; (void)n_in; (void)out_size;

    hipMemsetAsync(deg,  0, (size_t)NNP*4, stream);
    hipMemsetAsync(pool, 0, (size_t)NG*2*H*4, stream);
    hipMemsetAsync(cnt,  0, (size_t)2*NG*4, stream);

    deg_kernel        <<<(EE + 255)/256, 256, 0, stream>>>(eib, eiv, deg);
    bsum_kernel       <<<NBLK, 256, 0, stream>>>(deg, bsum);
    bscan_kernel      <<<1, 256, 0, stream>>>(bsum, boff);
    scan_final_kernel <<<NBLK, 256, 0, stream>>>(deg, boff, row_ptr, cursor);
    csr_fill_kernel   <<<(EE + 255)/256, 256, 0, stream>>>(eib, eiv, cursor, csr_src);
    fold_kernel       <<<STEPS*H, 128, 0, stream>>>(ggc_w, gru_w_ih, Bfold);
    pack_kernel       <<<(STEPS*WCAT_STEP + 255)/256, 256, 0, stream>>>(Bfold, gru_w_hh, Wcat);

    emb_kernel<<<NN/8, 128, 0, stream>>>(x_b, x_v, W_emb_b, W_emb_v, hb0);

    u16* hbs[2] = { hb0, hb1 };
    for (int s = 0; s < STEPS; ++s){
        u16* hin  = hbs[s & 1];
        u16* hout = hbs[(s + 1) & 1];
        agg_kernel     <<<NN/4, 256, 0, stream>>>(hin, row_ptr, csr_src, aggb);
        gru_mfma_kernel<<<dim3(NN/64, 2), 256, 0, stream>>>(aggb, hin, hout,
                                                            Wcat + (size_t)s*WCAT_STEP,
                                                            gru_b_ih, gru_b_hh);
    }

    pool_kernel<<<NN/32, 128, 0, stream>>>(hb0, batch_b, batch_v, pool);
    cnt_kernel <<<(NN + 255)/256, 256, 0, stream>>>(batch_b, batch_v, cnt);
    head_kernel<<<NG, 256, 0, stream>>>(pool, cnt, W1, b1, W2, b2, out);
}

// Round 6
// 937.142 us; speedup vs baseline: 4.8494x; 1.1271x over previous
//
#include <hip/hip_runtime.h>
#include <hip/hip_bf16.h>
#include <math.h>

#define N_NODES   100000
#define N_EDGES   600000
#define NG        64
#define H         128
#define STEPS     4
#define FB        90
#define FV        20
#define NN        (2*N_NODES)   /* 200000 combined nodes */
#define EE        (2*N_EDGES)   /* 1200000 combined edges */
#define BSTR      40            /* LDS row stride in shorts for A tiles */
#define NBLK      196           /* scan blocks: 196*1024 = 200704 >= NN */
#define NNP       (NBLK*1024)   /* padded degree array length */

#define WCAT_KC   (12*64*8)       /* shorts per (s,b1,kc) fragment chunk = 6144 (12KB) */
#define WCAT_HALF (8*WCAT_KC)     /* per (s,b1) */
#define WCAT_STEP (2*WCAT_HALF)   /* per step  */

typedef unsigned short u16;
typedef __attribute__((ext_vector_type(8))) __bf16 bf16x8;
typedef __attribute__((ext_vector_type(4))) float  floatx4;

static __device__ __forceinline__ float bf16_lo(unsigned u){ return __uint_as_float(u << 16); }
static __device__ __forceinline__ float bf16_hi(unsigned u){ return __uint_as_float(u & 0xffff0000u); }
static __device__ __forceinline__ u16 f2bf(float f){
    union { float f; unsigned u; } v; v.f = f;
    unsigned r = v.u + 0x7fffu + ((v.u >> 16) & 1u);
    return (u16)(r >> 16);
}
static __device__ __forceinline__ float fastrcp(float x){ return __builtin_amdgcn_rcpf(x); }
// sigmoid(x) = rcp(1+e^-x); handles +-inf correctly (rcp(inf)=0)
static __device__ __forceinline__ float fsigmoid(float x){ return fastrcp(1.f + __expf(-x)); }
// tanh(x) = 1 - 2*rcp(1+e^{2x}); x->+inf: rcp(inf)=0 -> 1; x->-inf: 1-2 = -1
static __device__ __forceinline__ float ftanh(float x){ return 1.f - 2.f*fastrcp(1.f + __expf(2.f*x)); }

// ---------------- CSR construction ----------------

__global__ void deg_kernel(const int* __restrict__ eib, const int* __restrict__ eiv,
                           int* __restrict__ deg){
    int e = blockIdx.x*blockDim.x + threadIdx.x;
    if (e >= EE) return;
    int d;
    if (e < N_EDGES) d = eib[N_EDGES + e];
    else             d = eiv[N_EDGES + (e - N_EDGES)] + N_NODES;
    atomicAdd(&deg[d], 1);
}

__global__ __launch_bounds__(256) void bsum_kernel(const int* __restrict__ deg, int* __restrict__ bsum){
    int t = threadIdx.x;
    int4 v = reinterpret_cast<const int4*>(deg)[blockIdx.x*256 + t];
    int s = v.x + v.y + v.z + v.w;
    __shared__ int ss[256];
    ss[t] = s; __syncthreads();
    for (int off = 128; off > 0; off >>= 1){ if (t < off) ss[t] += ss[t + off]; __syncthreads(); }
    if (t == 0) bsum[blockIdx.x] = ss[0];
}

__global__ __launch_bounds__(256) void bscan_kernel(const int* __restrict__ bsum, int* __restrict__ boff){
    int t = threadIdx.x;
    int v = (t < NBLK) ? bsum[t] : 0;
    __shared__ int ss[256];
    ss[t] = v; __syncthreads();
    for (int off = 1; off < 256; off <<= 1){
        int u = (t >= off) ? ss[t - off] : 0;
        __syncthreads();
        ss[t] += u;
        __syncthreads();
    }
    boff[t] = ss[t] - v;   // exclusive
}

__global__ __launch_bounds__(256) void scan_final_kernel(const int* __restrict__ deg, const int* __restrict__ boff,
                                                         int* __restrict__ row_ptr, int* __restrict__ cursor){
    int t = threadIdx.x, b = blockIdx.x;
    int4 v = reinterpret_cast<const int4*>(deg)[b*256 + t];
    int s = v.x + v.y + v.z + v.w;
    __shared__ int ss[256];
    ss[t] = s; __syncthreads();
    for (int off = 1; off < 256; off <<= 1){
        int u = (t >= off) ? ss[t - off] : 0;
        __syncthreads();
        ss[t] += u;
        __syncthreads();
    }
    int base = boff[b] + ss[t] - s;
    int i0 = b*1024 + t*4;
    int e0 = base, e1 = e0 + v.x, e2 = e1 + v.y, e3 = e2 + v.z;
    if (i0 < NN){
        int4 w = make_int4(e0, e1, e2, e3);
        reinterpret_cast<int4*>(row_ptr)[i0 >> 2] = w;
        reinterpret_cast<int4*>(cursor)[i0 >> 2]  = w;
    }
    if (b == 0 && t == 0) row_ptr[NN] = EE;
}

__global__ void csr_fill_kernel(const int* __restrict__ eib, const int* __restrict__ eiv,
                                int* __restrict__ cursor, int* __restrict__ csr_src){
    int e = blockIdx.x*blockDim.x + threadIdx.x;
    if (e >= EE) return;
    int s, d;
    if (e < N_EDGES){ s = eib[e];                 d = eib[N_EDGES + e]; }
    else { int e2 = e - N_EDGES; s = eiv[e2] + N_NODES; d = eiv[N_EDGES + e2] + N_NODES; }
    int pos = atomicAdd(&cursor[d], 1);
    csr_src[pos] = s;
}

// ---------------- weight prep ----------------
// Fold the GGC weight into the GRU input weights (linearity of segment_sum):
//   Bfold[s][k][c] = sum_q Wg[s][k][q] * w_ih[c][q],  k in [0,128), c in [0,384)
__global__ __launch_bounds__(128) void fold_kernel(const float* __restrict__ ggc_w,
                                                   const float* __restrict__ w_ih,
                                                   float* __restrict__ Bfold){
    int blk = blockIdx.x;              // s*128 + k
    int s = blk >> 7, k = blk & 127;
    __shared__ float wg[128];
    int t = threadIdx.x;
    wg[t] = ggc_w[(size_t)s*H*H + (size_t)k*H + t];
    __syncthreads();
    for (int c = t; c < 384; c += 128){
        const float* wr = w_ih + (size_t)c*H;
        float acc = 0.f;
        for (int q = 0; q < 128; q += 4){
            float4 a = *reinterpret_cast<const float4*>(&wg[q]);
            float4 b = *reinterpret_cast<const float4*>(&wr[q]);
            acc += a.x*b.x + a.y*b.y + a.z*b.z + a.w*b.w;
        }
        Bfold[((size_t)s*H + k)*384 + c] = acc;
    }
}

// Pack B into fragment-major layout: Wcat[s][b1][kc][t(12)][lane(64)][v(8)]
__global__ void pack_kernel(const float* __restrict__ Bfold, const float* __restrict__ w_hh,
                            u16* __restrict__ Wcat){
    int idx = blockIdx.x*256 + threadIdx.x;
    if (idx >= STEPS*WCAT_STEP) return;
    int v    = idx & 7;
    int lane = (idx >> 3) & 63;
    int t    = (idx >> 9) % 12;
    int rem  = idx / (512*12);          // s*16 + b1*8 + kc
    int kc   = rem & 7;
    int b1   = (rem >> 3) & 1;
    int s    = rem >> 4;
    int col16 = lane & 15, l4 = lane >> 4;
    int k = kc*32 + l4*8 + v;
    int g = t >> 2, jj = t & 3;
    int c = (4*b1 + jj)*16 + col16;
    int gc = (g == 2) ? (256 + c) : (g*128 + c);
    float val;
    if (k < 128) val = Bfold[((size_t)s*H + k)*384 + gc];
    else         val = w_hh[(size_t)gc*H + (k - 128)];
    Wcat[idx] = f2bf(val);
}

// ---------------- embedding: hb = bf16(relu(x @ W_emb)) ----------------

__global__ __launch_bounds__(128) void emb_kernel(const float* __restrict__ xb, const float* __restrict__ xv,
                                                  const float* __restrict__ Wb, const float* __restrict__ Wv,
                                                  u16* __restrict__ hb){
    __shared__ float xs[8][FB];
    int j = threadIdx.x;
    int n0 = blockIdx.x * 8;
    const float* x; const float* W; int K; int xoff;
    if (n0 < N_NODES){ x = xb; W = Wb; K = FB; xoff = n0; }
    else             { x = xv; W = Wv; K = FV; xoff = n0 - N_NODES; }
    for (int i = j; i < 8*K; i += 128){ int r = i / K, c = i - r*K; xs[r][c] = x[(xoff + r)*K + c]; }
    __syncthreads();
    float acc[8];
    #pragma unroll
    for (int n = 0; n < 8; ++n) acc[n] = 0.f;
    for (int k = 0; k < K; ++k){
        float w = W[k*H + j];
        #pragma unroll
        for (int n = 0; n < 8; ++n) acc[n] = fmaf(xs[n][k], w, acc[n]);
    }
    #pragma unroll
    for (int n = 0; n < 8; ++n)
        hb[(size_t)(n0 + n)*H + j] = f2bf(fmaxf(acc[n], 0.f));
}

// ---------------- agg_raw[dst] = sum hb[src] ----------------
// One wave per node. 32 lanes cover a row (uint2 = 8B/lane); the two
// half-waves process different edges in parallel; 2x unroll -> 4 loads
// in flight. Cross-half combine via shfl_xor(32).

__global__ __launch_bounds__(256) void agg_kernel(const u16* __restrict__ hb,
                                                  const int* __restrict__ row_ptr,
                                                  const int* __restrict__ csr_src,
                                                  u16* __restrict__ aggb){
    int wid  = threadIdx.x >> 6;
    int lane = threadIdx.x & 63;
    int half = lane >> 5;          // 0/1: which edge of the pair
    int c    = lane & 31;          // uint2 index within the row
    int node = blockIdx.x*4 + wid;
    int beg = row_ptr[node], end = row_ptr[node+1];
    const uint2* rows = reinterpret_cast<const uint2*>(hb);
    float s0 = 0.f, s1 = 0.f, s2 = 0.f, s3 = 0.f;
    float t0 = 0.f, t1 = 0.f, t2 = 0.f, t3 = 0.f;
    int e = beg + half;
    for (; e + 2 < end; e += 4){
        int sA = csr_src[e];
        int sB = csr_src[e + 2];
        uint2 uA = rows[(size_t)sA*32 + c];
        uint2 uB = rows[(size_t)sB*32 + c];
        s0 += bf16_lo(uA.x); s1 += bf16_hi(uA.x); s2 += bf16_lo(uA.y); s3 += bf16_hi(uA.y);
        t0 += bf16_lo(uB.x); t1 += bf16_hi(uB.x); t2 += bf16_lo(uB.y); t3 += bf16_hi(uB.y);
    }
    if (e < end){
        int sA = csr_src[e];
        uint2 uA = rows[(size_t)sA*32 + c];
        s0 += bf16_lo(uA.x); s1 += bf16_hi(uA.x); s2 += bf16_lo(uA.y); s3 += bf16_hi(uA.y);
    }
    s0 += t0; s1 += t1; s2 += t2; s3 += t3;
    s0 += __shfl_xor(s0, 32); s1 += __shfl_xor(s1, 32);
    s2 += __shfl_xor(s2, 32); s3 += __shfl_xor(s3, 32);
    if (half == 0){
        uint2 o;
        o.x = (unsigned)f2bf(s0) | ((unsigned)f2bf(s1) << 16);
        o.y = (unsigned)f2bf(s2) | ((unsigned)f2bf(s3) << 16);
        reinterpret_cast<uint2*>(aggb)[(size_t)node*32 + c] = o;
    }
}

// ---------------- fused GRU via MFMA (bf16 state, fast gate math) ----------------
// grid (NN/64, 2). Block: 64 rows x 256 B-cols. 16 acc tiles = 64 AGPR.

__global__ __launch_bounds__(256, 3) void gru_mfma_kernel(const u16* __restrict__ aggb,
                                                          const u16* __restrict__ hb_in,
                                                          u16* __restrict__ hb_out,
                                                          const u16* __restrict__ Wcat,  /* this step: [2][8][12][64][8] */
                                                          const float* __restrict__ b_ih,
                                                          const float* __restrict__ b_hh){
    __shared__ u16 Bs[WCAT_KC];      // 12 KB, fragment-major
    __shared__ u16 As[64*BSTR];      // 5 KB
    const int t = threadIdx.x;
    const int wid = t >> 6, lane = t & 63;
    const int l15 = lane & 15, l4 = lane >> 4;
    const int n0 = blockIdx.x * 64;
    const int b1 = blockIdx.y;
    const u16* Wsrc = Wcat + (size_t)b1*WCAT_HALF;

    floatx4 accR[4], accZ[4], accNi[4], accNh[4];
    #pragma unroll
    for (int i = 0; i < 4; ++i){
        accR[i] = (floatx4){0.f,0.f,0.f,0.f};  accZ[i]  = (floatx4){0.f,0.f,0.f,0.f};
        accNi[i] = (floatx4){0.f,0.f,0.f,0.f}; accNh[i] = (floatx4){0.f,0.f,0.f,0.f};
    }

    for (int kc = 0; kc < 8; ++kc){
        __syncthreads();
        {   // stage B: 768 int4, fragment-major -> fully coalesced, conflict-free
            const u16* src = Wsrc + (size_t)kc*WCAT_KC;
            #pragma unroll
            for (int p = 0; p < 3; ++p){
                int i = t + p*256;
                *reinterpret_cast<int4*>(&Bs[i*8]) = *reinterpret_cast<const int4*>(src + (size_t)i*8);
            }
        }
        {   // stage A: 64 rows x 32 shorts
            int row = t >> 2, part = t & 3;
            const u16* srcA = (kc < 4) ? aggb : hb_in;
            const int4 v = *reinterpret_cast<const int4*>(srcA + (size_t)(n0 + row)*H + (kc & 3)*32 + part*8);
            *reinterpret_cast<int4*>(&As[row*BSTR + part*8]) = v;
        }
        __syncthreads();
        bf16x8 aF = *reinterpret_cast<const bf16x8*>(&As[(wid*16 + l15)*BSTR + l4*8]);
        if (kc < 4){
            #pragma unroll
            for (int j = 0; j < 4; ++j){
                bf16x8 bR = *reinterpret_cast<const bf16x8*>(&Bs[((0*4 + j)*64 + lane)*8]);
                bf16x8 bZ = *reinterpret_cast<const bf16x8*>(&Bs[((1*4 + j)*64 + lane)*8]);
                bf16x8 bN = *reinterpret_cast<const bf16x8*>(&Bs[((2*4 + j)*64 + lane)*8]);
                accR[j]  = __builtin_amdgcn_mfma_f32_16x16x32_bf16(aF, bR, accR[j], 0, 0, 0);
                accZ[j]  = __builtin_amdgcn_mfma_f32_16x16x32_bf16(aF, bZ, accZ[j], 0, 0, 0);
                accNi[j] = __builtin_amdgcn_mfma_f32_16x16x32_bf16(aF, bN, accNi[j], 0, 0, 0);
            }
        } else {
            #pragma unroll
            for (int j = 0; j < 4; ++j){
                bf16x8 bR = *reinterpret_cast<const bf16x8*>(&Bs[((0*4 + j)*64 + lane)*8]);
                bf16x8 bZ = *reinterpret_cast<const bf16x8*>(&Bs[((1*4 + j)*64 + lane)*8]);
                bf16x8 bN = *reinterpret_cast<const bf16x8*>(&Bs[((2*4 + j)*64 + lane)*8]);
                accR[j]  = __builtin_amdgcn_mfma_f32_16x16x32_bf16(aF, bR, accR[j], 0, 0, 0);
                accZ[j]  = __builtin_amdgcn_mfma_f32_16x16x32_bf16(aF, bZ, accZ[j], 0, 0, 0);
                accNh[j] = __builtin_amdgcn_mfma_f32_16x16x32_bf16(aF, bN, accNh[j], 0, 0, 0);
            }
        }
    }

    const int rowb = n0 + wid*16 + l4*4;
    #pragma unroll
    for (int jj = 0; jj < 4; ++jj){
        int col = (4*b1 + jj)*16 + l15;
        float br  = b_ih[col]       + b_hh[col];
        float bz  = b_ih[128 + col] + b_hh[128 + col];
        float bin = b_ih[256 + col];
        float bhn = b_hh[256 + col];
        #pragma unroll
        for (int rg = 0; rg < 4; ++rg){
            int row = rowb + rg;
            float r   = fsigmoid(accR[jj][rg] + br);
            float z   = fsigmoid(accZ[jj][rg] + bz);
            float nn_ = ftanh(accNi[jj][rg] + bin + r*(accNh[jj][rg] + bhn));
            float hold = bf16_lo((unsigned)hb_in[(size_t)row*H + col]);
            float hnew = (1.f - z)*nn_ + z*hold;
            hb_out[(size_t)row*H + col] = f2bf(hnew);
        }
    }
}

// ---------------- pooling (bf16 state in) ----------------

__global__ __launch_bounds__(128) void pool_kernel(const u16* __restrict__ hb,
                                                   const int* __restrict__ batch_b, const int* __restrict__ batch_v,
                                                   float* __restrict__ pool){
    int j  = threadIdx.x;
    int n0 = blockIdx.x * 32;
    bool voro = (n0 >= N_NODES);
    int colbase = voro ? 128 : 0;
    int gcur = -1; float acc = 0.f;
    for (int r = 0; r < 32; ++r){
        int node = n0 + r;
        int g = voro ? batch_v[node - N_NODES] : batch_b[node];
        if (g != gcur){
            if (gcur >= 0) atomicAdd(&pool[gcur*256 + colbase + j], acc);
            acc = 0.f; gcur = g;
        }
        acc += fmaxf(bf16_lo((unsigned)hb[(size_t)node*H + j]), 0.f);
    }
    if (gcur >= 0) atomicAdd(&pool[gcur*256 + colbase + j], acc);
}

__global__ __launch_bounds__(256) void cnt_kernel(const int* __restrict__ batch_b, const int* __restrict__ batch_v,
                                                  int* __restrict__ cnt){
    __shared__ int bins[128];
    int t = threadIdx.x;
    if (t < 128) bins[t] = 0;
    __syncthreads();
    int i = blockIdx.x*256 + t;
    if (i < NN){
        int g = (i < N_NODES) ? batch_b[i] : 64 + batch_v[i - N_NODES];
        atomicAdd(&bins[g], 1);
    }
    __syncthreads();
    if (t < 128 && bins[t] > 0) atomicAdd(&cnt[t], bins[t]);
}

// ---------------- output head ----------------

__global__ __launch_bounds__(256) void head_kernel(const float* __restrict__ pool, const int* __restrict__ cnt,
                                                   const float* __restrict__ W1, const float* __restrict__ b1,
                                                   const float* __restrict__ W2, const float* __restrict__ b2,
                                                   float* __restrict__ out){
    __shared__ float gs[256];
    __shared__ float wsum[4];
    int b = blockIdx.x, j = threadIdx.x;
    int c = (j < 128) ? cnt[b] : cnt[64 + b];
    float denom = (float)((c > 1) ? c : 1);
    gs[j] = pool[b*256 + j] / denom;
    __syncthreads();
    float acc = b1[j];
    for (int k = 0; k < 256; ++k) acc = fmaf(gs[k], W1[k*256 + j], acc);
    float y = fmaxf(acc, 0.f) * W2[j];
    #pragma unroll
    for (int off = 32; off > 0; off >>= 1) y += __shfl_down(y, off, 64);
    if ((j & 63) == 0) wsum[j >> 6] = y;
    __syncthreads();
    if (j == 0){
        float x = wsum[0] + wsum[1] + wsum[2] + wsum[3] + b2[0];
        float sp = (x > 0.f) ? x + log1pf(expf(-x)) : log1pf(expf(x));
        out[b] = sp;
    }
}

// ---------------- launch ----------------

extern "C" void kernel_launch(void* const* d_in, const int* in_sizes, int n_in,
                              void* d_out, int out_size, void* d_ws, size_t ws_size,
                              hipStream_t stream){
    const float* x_b      = (const float*)d_in[0];
    const int*   eib      = (const int*)  d_in[1];
    const int*   batch_b  = (const int*)  d_in[2];
    const float* x_v      = (const float*)d_in[3];
    const int*   eiv      = (const int*)  d_in[4];
    const int*   batch_v  = (const int*)  d_in[5];
    const float* W_emb_b  = (const float*)d_in[6];
    const float* W_emb_v  = (const float*)d_in[7];
    const float* ggc_w    = (const float*)d_in[8];
    const float* gru_w_ih = (const float*)d_in[9];
    const float* gru_w_hh = (const float*)d_in[10];
    const float* gru_b_ih = (const float*)d_in[11];
    const float* gru_b_hh = (const float*)d_in[12];
    const float* W1       = (const float*)d_in[13];
    const float* b1       = (const float*)d_in[14];
    const float* W2       = (const float*)d_in[15];
    const float* b2       = (const float*)d_in[16];
    float* out = (float*)d_out;

    char* ws = (char*)d_ws;
    size_t off = 0;
    auto alloc = [&](size_t bytes)->char*{
        char* p = ws + off; off += (bytes + 255)/256*256; return p;
    };
    u16*   hb0      = (u16*)   alloc((size_t)NN*H*2);        //  51.2 MB
    u16*   hb1      = (u16*)   alloc((size_t)NN*H*2);        //  51.2 MB
    u16*   aggb     = (u16*)   alloc((size_t)NN*H*2);        //  51.2 MB
    float* Bfold    = (float*) alloc((size_t)STEPS*H*384*4); // 786 KB
    u16*   Wcat     = (u16*)   alloc((size_t)STEPS*WCAT_STEP*2);
    int*   row_ptr  = (int*)   alloc((size_t)(NN+1)*4);
    int*   deg      = (int*)   alloc((size_t)NNP*4);
    int*   cursor   = (int*)   alloc((size_t)NN*4);
    int*   csr_src  = (int*)   alloc((size_t)EE*4);
    int*   bsum     = (int*)   alloc((size_t)256*4);
    int*   boff     = (int*)   alloc((size_t)256*4);
    float* pool     = (float*) alloc((size_t)NG*2*H*4);
    int*   cnt      = (int*)   alloc((size_t)2*NG*4);
    (void)ws_size; (void)in_sizes; (void)n_in; (void)out_size;

    hipMemsetAsync(deg,  0, (size_t)NNP*4, stream);
    hipMemsetAsync(pool, 0, (size_t)NG*2*H*4, stream);
    hipMemsetAsync(cnt,  0, (size_t)2*NG*4, stream);

    deg_kernel        <<<(EE + 255)/256, 256, 0, stream>>>(eib, eiv, deg);
    bsum_kernel       <<<NBLK, 256, 0, stream>>>(deg, bsum);
    bscan_kernel      <<<1, 256, 0, stream>>>(bsum, boff);
    scan_final_kernel <<<NBLK, 256, 0, stream>>>(deg, boff, row_ptr, cursor);
    csr_fill_kernel   <<<(EE + 255)/256, 256, 0, stream>>>(eib, eiv, cursor, csr_src);
    fold_kernel       <<<STEPS*H, 128, 0, stream>>>(ggc_w, gru_w_ih, Bfold);
    pack_kernel       <<<(STEPS*WCAT_STEP + 255)/256, 256, 0, stream>>>(Bfold, gru_w_hh, Wcat);

    emb_kernel<<<NN/8, 128, 0, stream>>>(x_b, x_v, W_emb_b, W_emb_v, hb0);

    u16* hbs[2] = { hb0, hb1 };
    for (int s = 0; s < STEPS; ++s){
        u16* hin  = hbs[s & 1];
        u16* hout = hbs[(s + 1) & 1];
        agg_kernel     <<<NN/4, 256, 0, stream>>>(hin, row_ptr, csr_src, aggb);
        gru_mfma_kernel<<<dim3(NN/64, 2), 256, 0, stream>>>(aggb, hin, hout,
                                                            Wcat + (size_t)s*WCAT_STEP,
                                                            gru_b_ih, gru_b_hh);
    }

    pool_kernel<<<NN/32, 128, 0, stream>>>(hb0, batch_b, batch_v, pool);
    cnt_kernel <<<(NN + 255)/256, 256, 0, stream>>>(batch_b, batch_v, cnt);
    head_kernel<<<NG, 256, 0, stream>>>(pool, cnt, W1, b1, W2, b2, out);
}